// Round 3
// baseline (350.200 us; speedup 1.0000x reference)
//
#include <hip/hip_runtime.h>
#include <stdint.h>
#include <math.h>

// PANConcDQL round 20 -- math identical to r19 (passed, absmax 0.0).
// r19 evidence: all top-5 dispatches are the 40us harness fill; our kernels
// sum to ~50-60us by cycle count, yet total is 201us -> ~80-100us of
// inter-dispatch launch gaps (9 dispatches x ~10us, cf. rocprof.md).
// Change: fuse memset+scatter+extract+mid+pool+gat+head into ONE persistent
// kernel (192 blocks x 512, all co-resident: <=128 VGPR, 8.9KB LDS) with
// one-shot device-scope grid barriers between phases (zeroed via a 256B
// memset). Phase bodies are r19 verbatim -> bit-exact. Dispatches 9 -> 3.
#define BB   16
#define NPn  512
#define LLp  20
#define NAa  50
#define KKk  410
#define NNt  (BB * NPn)   // 8192
#define EEe  (6 * NNt)    // 49152
#define NFf  13
#define KPAD 416
#define KP2  448          // padded GAT staging width (7*64)
#define EPSf 1e-5f
#define QCLMP 1e6f
#define MAXD 28
#define PADR 512
#define NBLK 192
#define NWAVE (NBLK * 8)  // 1536

__device__ __forceinline__ float r17_sane(float v) {
    if (!(v == v)) return 0.0f;
    return fminf(fmaxf(v, -1e15f), 1e15f);
}

// one-shot grid barrier: per-phase counter (no reuse -> no generation races).
// agent-scope acq_rel RMW + acquire spin; __threadfence belt-and-suspenders
// for cross-XCD L2 writeback/invalidate (guide G16).
__device__ __forceinline__ void r20_gridbar(uint32_t* bar) {
    __syncthreads();
    if (threadIdx.x == 0) {
        __threadfence();
        __hip_atomic_fetch_add(bar, 1u, __ATOMIC_ACQ_REL, __HIP_MEMORY_SCOPE_AGENT);
        while (__hip_atomic_load(bar, __ATOMIC_ACQUIRE, __HIP_MEMORY_SCOPE_AGENT)
               < (uint32_t)NBLK) {
            __builtin_amdgcn_s_sleep(2);
        }
        __threadfence();
    }
    __syncthreads();
}

// wave-max of per-thread real degree (pads are PADR).
__device__ __forceinline__ int r19_wmaxdeg(const int (&iF)[MAXD]) {
    int deg = 0;
#pragma unroll
    for (int j = 0; j < MAXD; ++j) deg += (iF[j] != PADR) ? 1 : 0;
#pragma unroll
    for (int off = 32; off; off >>= 1) {
        const int o = __shfl_xor(deg, off);
        deg = o > deg ? o : deg;
    }
    return deg;
}

// chunked gather-sum: compile-time indices only; dm is wave-uniform.
__device__ __forceinline__ float r19_gsum(const float* __restrict__ rp,
                                          const int (&iF)[MAXD], int dm) {
    float s = 0.0f;
    s += rp[iF[0]]; s += rp[iF[1]]; s += rp[iF[2]]; s += rp[iF[3]];
    if (dm > 4) {
        s += rp[iF[4]]; s += rp[iF[5]]; s += rp[iF[6]]; s += rp[iF[7]];
        if (dm > 8) {
            s += rp[iF[8]]; s += rp[iF[9]]; s += rp[iF[10]]; s += rp[iF[11]];
            if (dm > 12) {
                s += rp[iF[12]]; s += rp[iF[13]]; s += rp[iF[14]]; s += rp[iF[15]];
                if (dm > 16) {
                    s += rp[iF[16]]; s += rp[iF[17]]; s += rp[iF[18]]; s += rp[iF[19]];
                    if (dm > 20) {
                        s += rp[iF[20]]; s += rp[iF[21]]; s += rp[iF[22]]; s += rp[iF[23]];
                        if (dm > 24) {
                            s += rp[iF[24]]; s += rp[iF[25]]; s += rp[iF[26]]; s += rp[iF[27]];
                        }
                    }
                }
            }
        }
    }
    return s;
}

// chunked gather-OR over uint2 planes (b64 reads).
__device__ __forceinline__ void r19_gor(const uint2* __restrict__ rp,
                                        const int (&iF)[MAXD], int dm, uint2& r) {
    {
        const uint2 v0 = rp[iF[0]], v1 = rp[iF[1]], v2 = rp[iF[2]], v3 = rp[iF[3]];
        r.x |= v0.x | v1.x | v2.x | v3.x;
        r.y |= v0.y | v1.y | v2.y | v3.y;
    }
    if (dm > 4) {
        const uint2 v0 = rp[iF[4]], v1 = rp[iF[5]], v2 = rp[iF[6]], v3 = rp[iF[7]];
        r.x |= v0.x | v1.x | v2.x | v3.x;
        r.y |= v0.y | v1.y | v2.y | v3.y;
        if (dm > 8) {
            const uint2 w0 = rp[iF[8]], w1 = rp[iF[9]], w2 = rp[iF[10]], w3 = rp[iF[11]];
            r.x |= w0.x | w1.x | w2.x | w3.x;
            r.y |= w0.y | w1.y | w2.y | w3.y;
            if (dm > 12) {
                const uint2 u0 = rp[iF[12]], u1 = rp[iF[13]], u2 = rp[iF[14]], u3 = rp[iF[15]];
                r.x |= u0.x | u1.x | u2.x | u3.x;
                r.y |= u0.y | u1.y | u2.y | u3.y;
                if (dm > 16) {
                    const uint2 a0 = rp[iF[16]], a1 = rp[iF[17]], a2 = rp[iF[18]], a3 = rp[iF[19]];
                    r.x |= a0.x | a1.x | a2.x | a3.x;
                    r.y |= a0.y | a1.y | a2.y | a3.y;
                    if (dm > 20) {
                        const uint2 b0 = rp[iF[20]], b1 = rp[iF[21]], b2 = rp[iF[22]], b3 = rp[iF[23]];
                        r.x |= b0.x | b1.x | b2.x | b3.x;
                        r.y |= b0.y | b1.y | b2.y | b3.y;
                        if (dm > 24) {
                            const uint2 c0 = rp[iF[24]], c1 = rp[iF[25]], c2 = rp[iF[26]], c3 = rp[iF[27]];
                            r.x |= c0.x | c1.x | c2.x | c3.x;
                            r.y |= c0.y | c1.y | c2.y | c3.y;
                        }
                    }
                }
            }
        }
    }
}

struct R20P {
    const float* x; const int* ei; const int* cnid; const int* amask;
    const float* panw; const float* l1w; const float* l1b;
    const float* n1w; const float* n1b; const float* n1ms;
    const float* poolp; const float* poolb;
    const float* gwl; const float* gbl; const float* gwr; const float* gbr;
    const float* gatt; const float* gbias;
    const float* n2w; const float* n2b; const float* n2ms;
    const float* v1w; const float* v1b; const float* v2w; const float* v2b;
    const float* v3w; const float* v3b;
    const float* a1w; const float* a1b; const float* a2w; const float* a2b;
    const float* a3w; const float* a3b;
    uint32_t* fwdb; uint32_t* trsb; uint32_t* bar; uint32_t* Rb;
    unsigned short* csrF; unsigned short* csrT;
    float* h_raw; float* x1; float* colsum; float* g_raw;
    float* xpg; float4* xlg; int* kidxg; uint32_t* RTg;
    float* out;
};

// ---------------------------------------------------------------------------
// The persistent mega-kernel: 7 phases separated by grid barriers.
__global__ __launch_bounds__(512) void r20_mega(R20P p)
{
    __shared__ __align__(16) uint32_t sbuf[2208];   // 8832 B, reused per phase
    const int blk = blockIdx.x, t = threadIdx.x;
    const int gtid = blk * 512 + t;                 // 0..98303
    const int lane = t & 63, wv = t >> 6;

    // ---- phase 0: zero edge bitsets (1 MB as uint4) ----
    if (gtid < 65536) ((uint4*)p.fwdb)[gtid] = make_uint4(0u, 0u, 0u, 0u);
    r20_gridbar(p.bar + 0);

    // ---- phase 1: edge scatter -> bitsets ----
    if (gtid < EEe) {
        const int src = p.ei[gtid], dst = p.ei[EEe + gtid];
        atomicOr(&p.fwdb[(size_t)dst * 16 + ((src & 511) >> 5)], 1u << (src & 31));
        atomicOr(&p.trsb[(size_t)src * 16 + ((dst & 511) >> 5)], 1u << (dst & 31));
    }
    r20_gridbar(p.bar + 1);

    // ---- phase 2: bitset -> CSR planes ----
    if (gtid < 16384) {
        const int node = gtid & 8191;
        const uint32_t* bs = (gtid < 8192) ? (p.fwdb + (size_t)node * 16)
                                           : (p.trsb + (size_t)node * 16);
        unsigned short* cs = (gtid < 8192) ? p.csrF : p.csrT;
        int cnt = 0;
        for (int w = 0; w < 16; ++w) {
            uint32_t bits = bs[w];
            while (bits) {
                const int u = (w << 5) + __ffs(bits) - 1;
                bits &= bits - 1;
                if (cnt < MAXD) cs[(size_t)cnt * 8192 + node] = (unsigned short)u;
                ++cnt;
            }
        }
        for (int j = cnt; j < MAXD; ++j) cs[(size_t)j * 8192 + node] = PADR;
    }
    r20_gridbar(p.bar + 2);

    // ---- phase 3: mid (r19_mid verbatim; blk -> (b,y) of grid (16,12)) ----
    {
        const int b = blk / 12, y = blk % 12;
        const int node = b * 512 + t;
        int iF[MAXD];
#pragma unroll
        for (int j = 0; j < MAXD; ++j) iF[j] = (int)p.csrF[(size_t)j * 8192 + node];
        const int dmF = r19_wmaxdeg(iF);

        if (y < 4) {
            const int c = y;
            float* pa  = (float*)sbuf;             // 513
            float* pb  = (float*)(sbuf + 513);     // 513
            float* wsh = (float*)(sbuf + 1026);    // 21
            if (t < 21) wsh[t] = p.panw[t];

            pa[t] = 1.0f;
            if (t == 0) { pa[512] = 0.0f; pb[512] = 0.0f; }
            __syncthreads();
            float dacc = wsh[0];
            {
                float* rp = pa; float* rn = pb;
                for (int i = 1; i <= LLp; ++i) {
                    const float s = r19_gsum(rp, iF, dmF);
                    rn[t] = s;
                    dacc += wsh[i] * s;
                    __syncthreads();
                    float* tp = rp; rp = rn; rn = tp;
                }
            }
            const float d0 = (dacc > 0.0f) ? 1.0f / sqrtf(dacc) : 0.0f;

            int idx[MAXD];
            int dm2;
            if (c == 3) {
#pragma unroll
                for (int j = 0; j < MAXD; ++j) idx[j] = (int)p.csrT[(size_t)j * 8192 + node];
                dm2 = r19_wmaxdeg(idx);
            } else {
#pragma unroll
                for (int j = 0; j < MAXD; ++j) idx[j] = iF[j];
                dm2 = dmF;
            }
            float seed;
            if (c < 3) {
                float xw = 0.0f;
                const float* xr = p.x + (size_t)node * NFf;
                for (int f = 0; f < NFf; ++f) xw += xr[f] * p.l1w[f * 3 + c];
                seed = d0 * xw;
            } else {
                seed = d0;
            }
            pa[t] = seed;
            if (t == 0) { pa[512] = 0.0f; pb[512] = 0.0f; }
            __syncthreads();
            float acc = wsh[0] * seed;
            {
                float* rp = pa; float* rn = pb;
                for (int i = 1; i <= LLp; ++i) {
                    const float s = r19_gsum(rp, idx, dm2);
                    rn[t] = s;
                    acc += wsh[i] * s;
                    __syncthreads();
                    float* tp = rp; rp = rn; rn = tp;
                }
            }
            if (c < 3) p.h_raw[(size_t)node * 3 + c] = r17_sane(d0 * acc + p.l1b[c]);
            else       p.colsum[node] = r17_sane(d0 * acc);
        } else {
            const int q = y - 4;                   // plane pair {2q, 2q+1}
            uint2* R1 = (uint2*)sbuf;              // 513
            uint2* R2 = R1 + 513;                  // 513
            uint2 seed;
            seed.x = ((t >> 5) == 2 * q)     ? (1u << (t & 31)) : 0u;
            seed.y = ((t >> 5) == 2 * q + 1) ? (1u << (t & 31)) : 0u;
            R1[t] = seed;
            if (t == 0) {
                uint2 z; z.x = 0u; z.y = 0u;
                R1[512] = z; R2[512] = z;
            }
            __syncthreads();
            uint2* Rp = R1; uint2* Rn = R2;
            for (int i = 0; i < LLp; ++i) {
                uint2 r = Rp[t];
                r19_gor(Rp, iF, dmF, r);
                Rn[t] = r;
                __syncthreads();
                uint2* tp = Rp; Rp = Rn; Rn = tp;
            }
            *(uint2*)(&p.Rb[(size_t)node * 16 + 2 * q]) = Rp[t];
        }
    }
    r20_gridbar(p.bar + 3);

    // ---- phase 4: pool (blocks 0..15 only; r19_pool verbatim) ----
    if (blk < BB) {
        const int b = blk;
        float* sc   = (float*)sbuf;                // 512
        float* mv   = (float*)(sbuf + 512);        // 8
        float* wred = (float*)(sbuf + 520);        // 24
        float* xpS  = (float*)(sbuf + 544);        // 1248 (416*3)
        int*   kidx = (int*)(sbuf + 1792);         // 416
        const float inv_n = 1.0f / (float)NNt;

        float hv0[16], hv1[16], hv2[16];
        float p0 = 0.0f, p1 = 0.0f, p2 = 0.0f;
#pragma unroll
        for (int k = 0; k < 16; ++k) {
            const float* hr = p.h_raw + (size_t)(k * 512 + t) * 3;
            hv0[k] = hr[0]; hv1[k] = hr[1]; hv2[k] = hr[2];
            p0 += hv0[k]; p1 += hv1[k]; p2 += hv2[k];
        }
#pragma unroll
        for (int off = 32; off; off >>= 1) {
            p0 += __shfl_xor(p0, off); p1 += __shfl_xor(p1, off); p2 += __shfl_xor(p2, off);
        }
        if (lane == 0) { wred[wv * 3 + 0] = p0; wred[wv * 3 + 1] = p1; wred[wv * 3 + 2] = p2; }
        __syncthreads();
        if (t < 3) {
            float s = 0.0f;
            for (int w = 0; w < 8; ++w) s += wred[w * 3 + t];
            mv[t] = s * inv_n;
        }
        __syncthreads();
        const float mm0 = p.n1ms[0] * mv[0], mm1 = p.n1ms[1] * mv[1], mm2 = p.n1ms[2] * mv[2];
        float q0 = 0.0f, q1 = 0.0f, q2 = 0.0f;
#pragma unroll
        for (int k = 0; k < 16; ++k) {
            const float d0 = hv0[k] - mm0, d1 = hv1[k] - mm1, d2 = hv2[k] - mm2;
            q0 += d0 * d0; q1 += d1 * d1; q2 += d2 * d2;
        }
#pragma unroll
        for (int off = 32; off; off >>= 1) {
            q0 += __shfl_xor(q0, off); q1 += __shfl_xor(q1, off); q2 += __shfl_xor(q2, off);
        }
        if (lane == 0) { wred[wv * 3 + 0] = q0; wred[wv * 3 + 1] = q1; wred[wv * 3 + 2] = q2; }
        __syncthreads();
        if (t < 3) {
            float s = 0.0f;
            for (int w = 0; w < 8; ++w) s += wred[w * 3 + t];
            mv[3 + t] = s * inv_n;
        }
        __syncthreads();

        const float mmv[3] = { mm0, mm1, mm2 };
        float xv[3];
#pragma unroll
        for (int c = 0; c < 3; ++c) {
            const float iv = 1.0f / sqrtf(fmaxf(mv[3 + c], 0.0f) + EPSf);
            const float o  = p.h_raw[(size_t)(b * NPn + t) * 3 + c] - mmv[c];
            const float tt = p.n1w[c] * o * iv + p.n1b[c];
            xv[c] = fmaxf(tt, 0.0f);
            p.x1[(size_t)(b * NPn + t) * 3 + c] = xv[c];
        }
        float s = p.poolb[0] * (xv[0] * p.poolp[0] + xv[1] * p.poolp[1] + xv[2] * p.poolp[2])
                + p.poolb[1] * p.colsum[b * NPn + t];
        s = tanhf(s);
        if (!(s == s)) s = 0.0f;
        sc[t] = s;
        __syncthreads();

        int cnt = 0;
        for (int u = 0; u < NPn; u += 4) {
            const float4 s4 = *(const float4*)(sc + u);
            cnt += ((s4.x > s) || (s4.x == s && (u + 0) < t)) ? 1 : 0;
            cnt += ((s4.y > s) || (s4.y == s && (u + 1) < t)) ? 1 : 0;
            cnt += ((s4.z > s) || (s4.z == s && (u + 2) < t)) ? 1 : 0;
            cnt += ((s4.w > s) || (s4.w == s && (u + 3) < t)) ? 1 : 0;
        }
        if (cnt < KKk) {                       // rank-count bijection
            const float xp0 = xv[0] * s, xp1 = xv[1] * s, xp2 = xv[2] * s;
            kidx[cnt] = t;
            xpS[cnt * 3 + 0] = xp0;
            xpS[cnt * 3 + 1] = xp1;
            xpS[cnt * 3 + 2] = xp2;
            p.kidxg[b * KPAD + cnt] = t;
            p.xpg[(size_t)(b * KPAD + cnt) * 3 + 0] = xp0;
            p.xpg[(size_t)(b * KPAD + cnt) * 3 + 1] = xp1;
            p.xpg[(size_t)(b * KPAD + cnt) * 3 + 2] = xp2;
        }
        __syncthreads();

        float Wl[9];
#pragma unroll
        for (int i2 = 0; i2 < 9; ++i2) Wl[i2] = p.gwl[i2];
        const float Bl0 = p.gbl[0], Bl1 = p.gbl[1], Bl2 = p.gbl[2];
        if (t < KP2) {
            float xl0, xl1, xl2;
            uint32_t* RT = p.RTg + (size_t)b * 16 * KP2 + t;
            if (t < KKk) {
                const float c0 = xpS[t * 3 + 0];
                const float c1 = xpS[t * 3 + 1];
                const float c2 = xpS[t * 3 + 2];
                xl0 = c0 * Wl[0] + c1 * Wl[3] + c2 * Wl[6] + Bl0;
                xl1 = c0 * Wl[1] + c1 * Wl[4] + c2 * Wl[7] + Bl1;
                xl2 = c0 * Wl[2] + c1 * Wl[5] + c2 * Wl[8] + Bl2;
                const uint4* rr = (const uint4*)(p.Rb + (size_t)(b * NPn + kidx[t]) * 16);
                const uint4 r0 = rr[0], r1 = rr[1], r2 = rr[2], r3 = rr[3];
                RT[ 0 * KP2] = r0.x; RT[ 1 * KP2] = r0.y; RT[ 2 * KP2] = r0.z; RT[ 3 * KP2] = r0.w;
                RT[ 4 * KP2] = r1.x; RT[ 5 * KP2] = r1.y; RT[ 6 * KP2] = r1.z; RT[ 7 * KP2] = r1.w;
                RT[ 8 * KP2] = r2.x; RT[ 9 * KP2] = r2.y; RT[10 * KP2] = r2.z; RT[11 * KP2] = r2.w;
                RT[12 * KP2] = r3.x; RT[13 * KP2] = r3.y; RT[14 * KP2] = r3.z; RT[15 * KP2] = r3.w;
            } else {
                xl0 = 0.0f; xl1 = 0.0f; xl2 = 0.0f;
#pragma unroll
                for (int w = 0; w < 16; ++w) RT[w * KP2] = 0u;
            }
            p.xlg[(size_t)(b * KP2 + t)] = make_float4(xl0, xl1, xl2, 0.0f);
        }
    }
    r20_gridbar(p.bar + 4);

    // ---- phase 5: GAT (all blocks; grid-stride, one wave per row) ----
    {
        const int wvg = blk * 8 + wv;              // 0..1535
        float Wr[9];
#pragma unroll
        for (int k = 0; k < 9; ++k) Wr[k] = p.gwr[k];
        const float Br0 = p.gbr[0], Br1 = p.gbr[1], Br2 = p.gbr[2];
        const float At0 = p.gatt[0], At1 = p.gatt[1], At2 = p.gatt[2];
        const float Gb0 = p.gbias[0], Gb1 = p.gbias[1], Gb2 = p.gbias[2];

        for (int r = wvg; r < BB * KPAD; r += NWAVE) {
            const int b = r / KPAD, i = r - b * KPAD;
            if (i >= KKk) continue;
            const int bi = p.kidxg[b * KPAD + i];
            const float c0 = p.xpg[(size_t)(b * KPAD + i) * 3 + 0];
            const float c1 = p.xpg[(size_t)(b * KPAD + i) * 3 + 1];
            const float c2 = p.xpg[(size_t)(b * KPAD + i) * 3 + 2];
            const float xr0 = c0 * Wr[0] + c1 * Wr[3] + c2 * Wr[6] + Br0;
            const float xr1 = c0 * Wr[1] + c1 * Wr[4] + c2 * Wr[7] + Br1;
            const float xr2 = c0 * Wr[2] + c1 * Wr[5] + c2 * Wr[8] + Br2;

            const uint32_t mbit = 1u << (bi & 31);
            const uint32_t* Rw = p.RTg + (size_t)(b * 16 + (bi >> 5)) * KP2;
            const float4* xlb = p.xlg + (size_t)b * KP2;

            float mx = -3e38f, lsum = 0.0f, b0 = 0.0f, b1 = 0.0f, b2 = 0.0f;
#pragma unroll
            for (int it = 0; it < 7; ++it) {
                const int j = lane + it * 64;          // < 448, coalesced
                const uint32_t rw = Rw[j];
                const float4 xlv = xlb[j];
                const float xl0 = xlv.x, xl1 = xlv.y, xl2 = xlv.z;
                const bool valid = (rw & mbit) || (j == i);   // pads auto-invalid
                float e0 = xr0 + xl0; e0 = e0 > 0.0f ? e0 : 0.2f * e0;
                float e1 = xr1 + xl1; e1 = e1 > 0.0f ? e1 : 0.2f * e1;
                float e2 = xr2 + xl2; e2 = e2 > 0.0f ? e2 : 0.2f * e2;
                const float sv = At0 * e0 + At1 * e1 + At2 * e2;
                if (valid) {
                    if (sv > mx) {
                        const float rr = __expf(mx - sv);
                        lsum *= rr; b0 *= rr; b1 *= rr; b2 *= rr;
                        mx = sv;
                    }
                    const float pj = __expf(sv - mx);
                    lsum += pj;
                    b0 += pj * xl0; b1 += pj * xl1; b2 += pj * xl2;
                }
            }
#pragma unroll
            for (int off = 32; off; off >>= 1) {       // butterfly LSE merge
                const float mo = __shfl_xor(mx, off);
                const float lo = __shfl_xor(lsum, off);
                const float d0 = __shfl_xor(b0, off);
                const float d1 = __shfl_xor(b1, off);
                const float d2 = __shfl_xor(b2, off);
                const float M  = fmaxf(mx, mo);
                const float ea = __expf(mx - M), eb = __expf(mo - M);
                lsum = lsum * ea + lo * eb;
                b0 = b0 * ea + d0 * eb;
                b1 = b1 * ea + d1 * eb;
                b2 = b2 * ea + d2 * eb;
                mx = M;
            }
            if (lane == 0) {
                const float rl = 1.0f / fmaxf(lsum, 1e-30f);
                p.g_raw[(size_t)(b * KPAD + i) * 3 + 0] = r17_sane(b0 * rl + Gb0);
                p.g_raw[(size_t)(b * KPAD + i) * 3 + 1] = r17_sane(b1 * rl + Gb1);
                p.g_raw[(size_t)(b * KPAD + i) * 3 + 2] = r17_sane(b2 * rl + Gb2);
            }
        }
    }
    r20_gridbar(p.bar + 5);

    // ---- phase 6: head (blocks 0..15 only; r17_head verbatim, LDS carved) ----
    if (blk < BB) {
        const int b = blk;
        float* sm     = (float*)sbuf;
        float* wred   = sm;          // 24
        float* mv     = sm + 24;     // 6
        float* gp     = sm + 30;     // 3
        float* feat   = sm + 33;     // 19
        float* h1a    = sm + 52;     // 10
        float* h1v    = sm + 62;     // 10
        float* h2a    = sm + 72;     // 5
        float* h2v    = sm + 77;     // 5
        float* a3     = sm + 82;     // 50
        float* vout_s = sm + 132;    // 1
        float* amean_s= sm + 133;    // 1
        const float denom = 1.0f / (float)(BB * KKk);

        float gv0[13], gv1[13], gv2[13];
        float p0 = 0.0f, p1 = 0.0f, p2 = 0.0f;
#pragma unroll
        for (int k = 0; k < 13; ++k) {
            const int r = k * 512 + t;
            float q0 = 0.0f, q1 = 0.0f, q2 = 0.0f;
            if (r < BB * KKk) {
                const int bq = r / KKk, iq = r - bq * KKk;
                const float* gr = p.g_raw + (size_t)(bq * KPAD + iq) * 3;
                q0 = gr[0]; q1 = gr[1]; q2 = gr[2];
            }
            gv0[k] = q0; gv1[k] = q1; gv2[k] = q2;
            p0 += q0; p1 += q1; p2 += q2;
        }
#pragma unroll
        for (int off = 32; off; off >>= 1) {
            p0 += __shfl_xor(p0, off); p1 += __shfl_xor(p1, off); p2 += __shfl_xor(p2, off);
        }
        if (lane == 0) { wred[wv * 3 + 0] = p0; wred[wv * 3 + 1] = p1; wred[wv * 3 + 2] = p2; }
        __syncthreads();
        if (t < 3) {
            float s = 0.0f;
            for (int w = 0; w < 8; ++w) s += wred[w * 3 + t];
            mv[t] = s * denom;
        }
        __syncthreads();
        const float mm0 = p.n2ms[0] * mv[0], mm1 = p.n2ms[1] * mv[1], mm2 = p.n2ms[2] * mv[2];
        float q0a = 0.0f, q1a = 0.0f, q2a = 0.0f;
#pragma unroll
        for (int k = 0; k < 13; ++k) {
            const int r = k * 512 + t;
            if (r < BB * KKk) {
                const float d0 = gv0[k] - mm0, d1 = gv1[k] - mm1, d2 = gv2[k] - mm2;
                q0a += d0 * d0; q1a += d1 * d1; q2a += d2 * d2;
            }
        }
#pragma unroll
        for (int off = 32; off; off >>= 1) {
            q0a += __shfl_xor(q0a, off); q1a += __shfl_xor(q1a, off); q2a += __shfl_xor(q2a, off);
        }
        if (lane == 0) { wred[wv * 3 + 0] = q0a; wred[wv * 3 + 1] = q1a; wred[wv * 3 + 2] = q2a; }
        __syncthreads();
        if (t < 3) {
            float s = 0.0f;
            for (int w = 0; w < 8; ++w) s += wred[w * 3 + t];
            mv[3 + t] = s * denom;
        }
        __syncthreads();

        const float mmv[3] = { mm0, mm1, mm2 };
        float s3[3] = { 0.0f, 0.0f, 0.0f };
        if (t < KKk) {
            const size_t r = (size_t)(b * KPAD + t) * 3;
#pragma unroll
            for (int c = 0; c < 3; ++c) {
                const float iv = 1.0f / sqrtf(fmaxf(mv[3 + c], 0.0f) + EPSf);
                s3[c] = fmaxf((p.g_raw[r + c] - mmv[c]) * iv * p.n2w[c] + p.n2b[c], 0.0f);
            }
        }
        float g0 = s3[0], g1 = s3[1], g2 = s3[2];
#pragma unroll
        for (int off = 32; off; off >>= 1) {
            g0 += __shfl_xor(g0, off); g1 += __shfl_xor(g1, off); g2 += __shfl_xor(g2, off);
        }
        if (lane == 0) { wred[wv * 3 + 0] = g0; wred[wv * 3 + 1] = g1; wred[wv * 3 + 2] = g2; }
        __syncthreads();
        if (t < 3) {
            float s = 0.0f;
            for (int w = 0; w < 8; ++w) s += wred[w * 3 + t];
            gp[t] = s;
        }
        __syncthreads();

        if (t < 19) {
            const int gidx = p.cnid[b] + b * KKk;      // faithful: pooled-K offsets
            float fv;
            if (t < 13)      fv = p.x[(size_t)gidx * NFf + t];
            else if (t < 16) fv = p.x1[(size_t)gidx * 3 + (t - 13)];
            else             fv = gp[t - 16];
            feat[t] = fv;
        }
        __syncthreads();

        if (t < 10) {
            float s = p.a1b[t];
            for (int f = 0; f < 19; ++f) s += feat[f] * p.a1w[f * 10 + t];
            h1a[t] = fmaxf(s, 0.0f);
        } else if (t >= 64 && t < 74) {
            const int j = t - 64;
            float s = p.v1b[j];
            for (int f = 0; f < 19; ++f) s += feat[f] * p.v1w[f * 10 + j];
            h1v[j] = fmaxf(s, 0.0f);
        }
        __syncthreads();
        if (t < 5) {
            float s = p.a2b[t];
            for (int k = 0; k < 10; ++k) s += h1a[k] * p.a2w[k * 5 + t];
            h2a[t] = fmaxf(s, 0.0f);
        } else if (t >= 64 && t < 69) {
            const int j = t - 64;
            float s = p.v2b[j];
            for (int k = 0; k < 10; ++k) s += h1v[k] * p.v2w[k * 5 + j];
            h2v[j] = fmaxf(s, 0.0f);
        }
        __syncthreads();
        if (t < 50) {
            float s = p.a3b[t];
            for (int k = 0; k < 5; ++k) s += h2a[k] * p.a3w[k * 50 + t];
            a3[t] = s;
        } else if (t == 64) {
            float s = p.v3b[0];
            for (int k = 0; k < 5; ++k) s += h2v[k] * p.v3w[k];
            *vout_s = s;
        }
        __syncthreads();
        if (t == 0) {
            float s = 0.0f;
            for (int k = 0; k < 50; ++k) s += a3[k];
            *amean_s = s * (1.0f / 50.0f);
        }
        __syncthreads();
        if (t < 50) {
            float q = *vout_s + a3[t] - *amean_s;
            if (!(q == q)) q = 0.0f;
            q = fminf(fmaxf(q, -QCLMP), QCLMP);
            p.out[b * NAa + t] = (p.amask[b * NAa + t] == 0) ? -1e8f : q;   // FP32
        }
    }
}

// ---------------------------------------------------------------------------
extern "C" void kernel_launch(void* const* d_in, const int* in_sizes, int n_in,
                              void* d_out, int out_size, void* d_ws, size_t ws_size,
                              hipStream_t stream) {
    (void)in_sizes; (void)n_in; (void)out_size;
    R20P p;
    p.x     = (const float*)d_in[0];
    p.ei    = (const int*)d_in[1];
    p.cnid  = (const int*)d_in[4];
    p.amask = (const int*)d_in[5];
    p.panw  = (const float*)d_in[6];
    p.l1w   = (const float*)d_in[7];
    p.l1b   = (const float*)d_in[8];
    p.n1w   = (const float*)d_in[9];
    p.n1b   = (const float*)d_in[10];
    p.n1ms  = (const float*)d_in[11];
    p.poolp = (const float*)d_in[12];
    p.poolb = (const float*)d_in[13];
    p.gwl   = (const float*)d_in[14];
    p.gbl   = (const float*)d_in[15];
    p.gwr   = (const float*)d_in[16];
    p.gbr   = (const float*)d_in[17];
    p.gatt  = (const float*)d_in[18];
    p.gbias = (const float*)d_in[19];
    p.n2w   = (const float*)d_in[20];
    p.n2b   = (const float*)d_in[21];
    p.n2ms  = (const float*)d_in[22];
    p.v1w   = (const float*)d_in[23];
    p.v1b   = (const float*)d_in[24];
    p.v2w   = (const float*)d_in[25];
    p.v2b   = (const float*)d_in[26];
    p.v3w   = (const float*)d_in[27];
    p.v3b   = (const float*)d_in[28];
    p.a1w   = (const float*)d_in[29];
    p.a1b   = (const float*)d_in[30];
    p.a2w   = (const float*)d_in[31];
    p.a2b   = (const float*)d_in[32];
    p.a3w   = (const float*)d_in[33];
    p.a3b   = (const float*)d_in[34];
    p.out   = (float*)d_out;

    // ws layout (bytes): fwdb 512K @0 | trsb 512K @512K | bar 256B @1M |
    //   Rb 512K | csrF | csrT | h_raw | x1 | colsum | g_raw | xpg | xlg(f4) |
    //   kidxg | RTg
    uint8_t* wsb = (uint8_t*)d_ws;
    p.fwdb = (uint32_t*)wsb;
    p.trsb = (uint32_t*)(wsb + 524288);
    p.bar  = (uint32_t*)(wsb + 1048576);
    p.Rb   = (uint32_t*)(wsb + 1048832);
    p.csrF = (unsigned short*)(wsb + 1048832 + 524288);
    p.csrT = p.csrF + (size_t)MAXD * 8192;
    p.h_raw  = (float*)(p.csrT + (size_t)MAXD * 8192);
    p.x1     = p.h_raw + (size_t)NNt * 3;
    p.colsum = p.x1 + (size_t)NNt * 3;
    p.g_raw  = p.colsum + NNt;
    p.xpg    = p.g_raw + (size_t)BB * KPAD * 3;
    p.xlg    = (float4*)(p.xpg + (size_t)BB * KPAD * 3);
    p.kidxg  = (int*)(p.xlg + (size_t)BB * KP2);
    p.RTg    = (uint32_t*)(p.kidxg + (size_t)BB * KPAD);
    const size_t needed = (size_t)((uint8_t*)(p.RTg + (size_t)BB * 16 * KP2) - wsb);
    if (ws_size < needed) return;

    hipMemsetAsync(p.bar, 0, 256, stream);               // one-shot barriers
    r20_mega<<<dim3(NBLK), dim3(512), 0, stream>>>(p);
}

// Round 4
// 284.015 us; speedup vs baseline: 1.2330x; 1.2330x over previous
//
#include <hip/hip_runtime.h>
#include <stdint.h>
#include <math.h>

// PANConcDQL round 21 -- math identical to r20 (passed, absmax 0.0).
// r20 post-mortem: mega=225us, VALU 3.5%, FETCH 6.9MB. Cause: the grid
// barrier's spin used ACQUIRE agent-scope loads -> buffer_inv (L1/L2
// invalidate) EVERY spin iteration from up to 176 idle blocks -> working
// blocks' L2 lines evicted continuously (elongated phases + 6.9MB fetch).
// Fix (only change): relaxed-spin barrier -- release fence, RELAXED
// fetch_add, RELAXED spin load (global_load sc1, no invalidate) with
// s_sleep backoff, ONE acquire fence at exit. Counters strided 64B.
#define BB   16
#define NPn  512
#define LLp  20
#define NAa  50
#define KKk  410
#define NNt  (BB * NPn)   // 8192
#define EEe  (6 * NNt)    // 49152
#define NFf  13
#define KPAD 416
#define KP2  448          // padded GAT staging width (7*64)
#define EPSf 1e-5f
#define QCLMP 1e6f
#define MAXD 28
#define PADR 512
#define NBLK 192
#define NWAVE (NBLK * 8)  // 1536
#define BARSTRIDE 16      // uint32s -> 64B per counter

__device__ __forceinline__ float r17_sane(float v) {
    if (!(v == v)) return 0.0f;
    return fminf(fmaxf(v, -1e15f), 1e15f);
}

// one-shot grid barrier, relaxed-spin form.
// release fence -> relaxed RMW -> relaxed spin (no per-iter invalidate)
// -> acquire fence at exit. Fence-fence synchronization (C++ mem model).
__device__ __forceinline__ void r21_gridbar(uint32_t* bar) {
    __syncthreads();
    if (threadIdx.x == 0) {
        __threadfence();   // release (agent scope): L2 writeback
        __hip_atomic_fetch_add(bar, 1u, __ATOMIC_RELAXED, __HIP_MEMORY_SCOPE_AGENT);
        while (__hip_atomic_load(bar, __ATOMIC_RELAXED, __HIP_MEMORY_SCOPE_AGENT)
               < (uint32_t)NBLK) {
            __builtin_amdgcn_s_sleep(8);
        }
        __threadfence();   // acquire: single invalidate at exit
    }
    __syncthreads();
}

// wave-max of per-thread real degree (pads are PADR).
__device__ __forceinline__ int r19_wmaxdeg(const int (&iF)[MAXD]) {
    int deg = 0;
#pragma unroll
    for (int j = 0; j < MAXD; ++j) deg += (iF[j] != PADR) ? 1 : 0;
#pragma unroll
    for (int off = 32; off; off >>= 1) {
        const int o = __shfl_xor(deg, off);
        deg = o > deg ? o : deg;
    }
    return deg;
}

// chunked gather-sum: compile-time indices only; dm is wave-uniform.
__device__ __forceinline__ float r19_gsum(const float* __restrict__ rp,
                                          const int (&iF)[MAXD], int dm) {
    float s = 0.0f;
    s += rp[iF[0]]; s += rp[iF[1]]; s += rp[iF[2]]; s += rp[iF[3]];
    if (dm > 4) {
        s += rp[iF[4]]; s += rp[iF[5]]; s += rp[iF[6]]; s += rp[iF[7]];
        if (dm > 8) {
            s += rp[iF[8]]; s += rp[iF[9]]; s += rp[iF[10]]; s += rp[iF[11]];
            if (dm > 12) {
                s += rp[iF[12]]; s += rp[iF[13]]; s += rp[iF[14]]; s += rp[iF[15]];
                if (dm > 16) {
                    s += rp[iF[16]]; s += rp[iF[17]]; s += rp[iF[18]]; s += rp[iF[19]];
                    if (dm > 20) {
                        s += rp[iF[20]]; s += rp[iF[21]]; s += rp[iF[22]]; s += rp[iF[23]];
                        if (dm > 24) {
                            s += rp[iF[24]]; s += rp[iF[25]]; s += rp[iF[26]]; s += rp[iF[27]];
                        }
                    }
                }
            }
        }
    }
    return s;
}

// chunked gather-OR over uint2 planes (b64 reads).
__device__ __forceinline__ void r19_gor(const uint2* __restrict__ rp,
                                        const int (&iF)[MAXD], int dm, uint2& r) {
    {
        const uint2 v0 = rp[iF[0]], v1 = rp[iF[1]], v2 = rp[iF[2]], v3 = rp[iF[3]];
        r.x |= v0.x | v1.x | v2.x | v3.x;
        r.y |= v0.y | v1.y | v2.y | v3.y;
    }
    if (dm > 4) {
        const uint2 v0 = rp[iF[4]], v1 = rp[iF[5]], v2 = rp[iF[6]], v3 = rp[iF[7]];
        r.x |= v0.x | v1.x | v2.x | v3.x;
        r.y |= v0.y | v1.y | v2.y | v3.y;
        if (dm > 8) {
            const uint2 w0 = rp[iF[8]], w1 = rp[iF[9]], w2 = rp[iF[10]], w3 = rp[iF[11]];
            r.x |= w0.x | w1.x | w2.x | w3.x;
            r.y |= w0.y | w1.y | w2.y | w3.y;
            if (dm > 12) {
                const uint2 u0 = rp[iF[12]], u1 = rp[iF[13]], u2 = rp[iF[14]], u3 = rp[iF[15]];
                r.x |= u0.x | u1.x | u2.x | u3.x;
                r.y |= u0.y | u1.y | u2.y | u3.y;
                if (dm > 16) {
                    const uint2 a0 = rp[iF[16]], a1 = rp[iF[17]], a2 = rp[iF[18]], a3 = rp[iF[19]];
                    r.x |= a0.x | a1.x | a2.x | a3.x;
                    r.y |= a0.y | a1.y | a2.y | a3.y;
                    if (dm > 20) {
                        const uint2 b0 = rp[iF[20]], b1 = rp[iF[21]], b2 = rp[iF[22]], b3 = rp[iF[23]];
                        r.x |= b0.x | b1.x | b2.x | b3.x;
                        r.y |= b0.y | b1.y | b2.y | b3.y;
                        if (dm > 24) {
                            const uint2 c0 = rp[iF[24]], c1 = rp[iF[25]], c2 = rp[iF[26]], c3 = rp[iF[27]];
                            r.x |= c0.x | c1.x | c2.x | c3.x;
                            r.y |= c0.y | c1.y | c2.y | c3.y;
                        }
                    }
                }
            }
        }
    }
}

struct R20P {
    const float* x; const int* ei; const int* cnid; const int* amask;
    const float* panw; const float* l1w; const float* l1b;
    const float* n1w; const float* n1b; const float* n1ms;
    const float* poolp; const float* poolb;
    const float* gwl; const float* gbl; const float* gwr; const float* gbr;
    const float* gatt; const float* gbias;
    const float* n2w; const float* n2b; const float* n2ms;
    const float* v1w; const float* v1b; const float* v2w; const float* v2b;
    const float* v3w; const float* v3b;
    const float* a1w; const float* a1b; const float* a2w; const float* a2b;
    const float* a3w; const float* a3b;
    uint32_t* fwdb; uint32_t* trsb; uint32_t* bar; uint32_t* Rb;
    unsigned short* csrF; unsigned short* csrT;
    float* h_raw; float* x1; float* colsum; float* g_raw;
    float* xpg; float4* xlg; int* kidxg; uint32_t* RTg;
    float* out;
};

// ---------------------------------------------------------------------------
// The persistent mega-kernel: 7 phases separated by grid barriers.
__global__ __launch_bounds__(512) void r21_mega(R20P p)
{
    __shared__ __align__(16) uint32_t sbuf[2208];   // 8832 B, reused per phase
    const int blk = blockIdx.x, t = threadIdx.x;
    const int gtid = blk * 512 + t;                 // 0..98303
    const int lane = t & 63, wv = t >> 6;

    // ---- phase 0: zero edge bitsets (1 MB as uint4) ----
    if (gtid < 65536) ((uint4*)p.fwdb)[gtid] = make_uint4(0u, 0u, 0u, 0u);
    r21_gridbar(p.bar + 0 * BARSTRIDE);

    // ---- phase 1: edge scatter -> bitsets ----
    if (gtid < EEe) {
        const int src = p.ei[gtid], dst = p.ei[EEe + gtid];
        atomicOr(&p.fwdb[(size_t)dst * 16 + ((src & 511) >> 5)], 1u << (src & 31));
        atomicOr(&p.trsb[(size_t)src * 16 + ((dst & 511) >> 5)], 1u << (dst & 31));
    }
    r21_gridbar(p.bar + 1 * BARSTRIDE);

    // ---- phase 2: bitset -> CSR planes ----
    if (gtid < 16384) {
        const int node = gtid & 8191;
        const uint32_t* bs = (gtid < 8192) ? (p.fwdb + (size_t)node * 16)
                                           : (p.trsb + (size_t)node * 16);
        unsigned short* cs = (gtid < 8192) ? p.csrF : p.csrT;
        int cnt = 0;
        for (int w = 0; w < 16; ++w) {
            uint32_t bits = bs[w];
            while (bits) {
                const int u = (w << 5) + __ffs(bits) - 1;
                bits &= bits - 1;
                if (cnt < MAXD) cs[(size_t)cnt * 8192 + node] = (unsigned short)u;
                ++cnt;
            }
        }
        for (int j = cnt; j < MAXD; ++j) cs[(size_t)j * 8192 + node] = PADR;
    }
    r21_gridbar(p.bar + 2 * BARSTRIDE);

    // ---- phase 3: mid (r19_mid verbatim; blk -> (b,y) of grid (16,12)) ----
    {
        const int b = blk / 12, y = blk % 12;
        const int node = b * 512 + t;
        int iF[MAXD];
#pragma unroll
        for (int j = 0; j < MAXD; ++j) iF[j] = (int)p.csrF[(size_t)j * 8192 + node];
        const int dmF = r19_wmaxdeg(iF);

        if (y < 4) {
            const int c = y;
            float* pa  = (float*)sbuf;             // 513
            float* pb  = (float*)(sbuf + 513);     // 513
            float* wsh = (float*)(sbuf + 1026);    // 21
            if (t < 21) wsh[t] = p.panw[t];

            pa[t] = 1.0f;
            if (t == 0) { pa[512] = 0.0f; pb[512] = 0.0f; }
            __syncthreads();
            float dacc = wsh[0];
            {
                float* rp = pa; float* rn = pb;
                for (int i = 1; i <= LLp; ++i) {
                    const float s = r19_gsum(rp, iF, dmF);
                    rn[t] = s;
                    dacc += wsh[i] * s;
                    __syncthreads();
                    float* tp = rp; rp = rn; rn = tp;
                }
            }
            const float d0 = (dacc > 0.0f) ? 1.0f / sqrtf(dacc) : 0.0f;

            int idx[MAXD];
            int dm2;
            if (c == 3) {
#pragma unroll
                for (int j = 0; j < MAXD; ++j) idx[j] = (int)p.csrT[(size_t)j * 8192 + node];
                dm2 = r19_wmaxdeg(idx);
            } else {
#pragma unroll
                for (int j = 0; j < MAXD; ++j) idx[j] = iF[j];
                dm2 = dmF;
            }
            float seed;
            if (c < 3) {
                float xw = 0.0f;
                const float* xr = p.x + (size_t)node * NFf;
                for (int f = 0; f < NFf; ++f) xw += xr[f] * p.l1w[f * 3 + c];
                seed = d0 * xw;
            } else {
                seed = d0;
            }
            pa[t] = seed;
            if (t == 0) { pa[512] = 0.0f; pb[512] = 0.0f; }
            __syncthreads();
            float acc = wsh[0] * seed;
            {
                float* rp = pa; float* rn = pb;
                for (int i = 1; i <= LLp; ++i) {
                    const float s = r19_gsum(rp, idx, dm2);
                    rn[t] = s;
                    acc += wsh[i] * s;
                    __syncthreads();
                    float* tp = rp; rp = rn; rn = tp;
                }
            }
            if (c < 3) p.h_raw[(size_t)node * 3 + c] = r17_sane(d0 * acc + p.l1b[c]);
            else       p.colsum[node] = r17_sane(d0 * acc);
        } else {
            const int q = y - 4;                   // plane pair {2q, 2q+1}
            uint2* R1 = (uint2*)sbuf;              // 513
            uint2* R2 = R1 + 513;                  // 513
            uint2 seed;
            seed.x = ((t >> 5) == 2 * q)     ? (1u << (t & 31)) : 0u;
            seed.y = ((t >> 5) == 2 * q + 1) ? (1u << (t & 31)) : 0u;
            R1[t] = seed;
            if (t == 0) {
                uint2 z; z.x = 0u; z.y = 0u;
                R1[512] = z; R2[512] = z;
            }
            __syncthreads();
            uint2* Rp = R1; uint2* Rn = R2;
            for (int i = 0; i < LLp; ++i) {
                uint2 r = Rp[t];
                r19_gor(Rp, iF, dmF, r);
                Rn[t] = r;
                __syncthreads();
                uint2* tp = Rp; Rp = Rn; Rn = tp;
            }
            *(uint2*)(&p.Rb[(size_t)node * 16 + 2 * q]) = Rp[t];
        }
    }
    r21_gridbar(p.bar + 3 * BARSTRIDE);

    // ---- phase 4: pool (blocks 0..15 only; r19_pool verbatim) ----
    if (blk < BB) {
        const int b = blk;
        float* sc   = (float*)sbuf;                // 512
        float* mv   = (float*)(sbuf + 512);        // 8
        float* wred = (float*)(sbuf + 520);        // 24
        float* xpS  = (float*)(sbuf + 544);        // 1248 (416*3)
        int*   kidx = (int*)(sbuf + 1792);         // 416
        const float inv_n = 1.0f / (float)NNt;

        float hv0[16], hv1[16], hv2[16];
        float p0 = 0.0f, p1 = 0.0f, p2 = 0.0f;
#pragma unroll
        for (int k = 0; k < 16; ++k) {
            const float* hr = p.h_raw + (size_t)(k * 512 + t) * 3;
            hv0[k] = hr[0]; hv1[k] = hr[1]; hv2[k] = hr[2];
            p0 += hv0[k]; p1 += hv1[k]; p2 += hv2[k];
        }
#pragma unroll
        for (int off = 32; off; off >>= 1) {
            p0 += __shfl_xor(p0, off); p1 += __shfl_xor(p1, off); p2 += __shfl_xor(p2, off);
        }
        if (lane == 0) { wred[wv * 3 + 0] = p0; wred[wv * 3 + 1] = p1; wred[wv * 3 + 2] = p2; }
        __syncthreads();
        if (t < 3) {
            float s = 0.0f;
            for (int w = 0; w < 8; ++w) s += wred[w * 3 + t];
            mv[t] = s * inv_n;
        }
        __syncthreads();
        const float mm0 = p.n1ms[0] * mv[0], mm1 = p.n1ms[1] * mv[1], mm2 = p.n1ms[2] * mv[2];
        float q0 = 0.0f, q1 = 0.0f, q2 = 0.0f;
#pragma unroll
        for (int k = 0; k < 16; ++k) {
            const float d0 = hv0[k] - mm0, d1 = hv1[k] - mm1, d2 = hv2[k] - mm2;
            q0 += d0 * d0; q1 += d1 * d1; q2 += d2 * d2;
        }
#pragma unroll
        for (int off = 32; off; off >>= 1) {
            q0 += __shfl_xor(q0, off); q1 += __shfl_xor(q1, off); q2 += __shfl_xor(q2, off);
        }
        if (lane == 0) { wred[wv * 3 + 0] = q0; wred[wv * 3 + 1] = q1; wred[wv * 3 + 2] = q2; }
        __syncthreads();
        if (t < 3) {
            float s = 0.0f;
            for (int w = 0; w < 8; ++w) s += wred[w * 3 + t];
            mv[3 + t] = s * inv_n;
        }
        __syncthreads();

        const float mmv[3] = { mm0, mm1, mm2 };
        float xv[3];
#pragma unroll
        for (int c = 0; c < 3; ++c) {
            const float iv = 1.0f / sqrtf(fmaxf(mv[3 + c], 0.0f) + EPSf);
            const float o  = p.h_raw[(size_t)(b * NPn + t) * 3 + c] - mmv[c];
            const float tt = p.n1w[c] * o * iv + p.n1b[c];
            xv[c] = fmaxf(tt, 0.0f);
            p.x1[(size_t)(b * NPn + t) * 3 + c] = xv[c];
        }
        float s = p.poolb[0] * (xv[0] * p.poolp[0] + xv[1] * p.poolp[1] + xv[2] * p.poolp[2])
                + p.poolb[1] * p.colsum[b * NPn + t];
        s = tanhf(s);
        if (!(s == s)) s = 0.0f;
        sc[t] = s;
        __syncthreads();

        int cnt = 0;
        for (int u = 0; u < NPn; u += 4) {
            const float4 s4 = *(const float4*)(sc + u);
            cnt += ((s4.x > s) || (s4.x == s && (u + 0) < t)) ? 1 : 0;
            cnt += ((s4.y > s) || (s4.y == s && (u + 1) < t)) ? 1 : 0;
            cnt += ((s4.z > s) || (s4.z == s && (u + 2) < t)) ? 1 : 0;
            cnt += ((s4.w > s) || (s4.w == s && (u + 3) < t)) ? 1 : 0;
        }
        if (cnt < KKk) {                       // rank-count bijection
            const float xp0 = xv[0] * s, xp1 = xv[1] * s, xp2 = xv[2] * s;
            kidx[cnt] = t;
            xpS[cnt * 3 + 0] = xp0;
            xpS[cnt * 3 + 1] = xp1;
            xpS[cnt * 3 + 2] = xp2;
            p.kidxg[b * KPAD + cnt] = t;
            p.xpg[(size_t)(b * KPAD + cnt) * 3 + 0] = xp0;
            p.xpg[(size_t)(b * KPAD + cnt) * 3 + 1] = xp1;
            p.xpg[(size_t)(b * KPAD + cnt) * 3 + 2] = xp2;
        }
        __syncthreads();

        float Wl[9];
#pragma unroll
        for (int i2 = 0; i2 < 9; ++i2) Wl[i2] = p.gwl[i2];
        const float Bl0 = p.gbl[0], Bl1 = p.gbl[1], Bl2 = p.gbl[2];
        if (t < KP2) {
            float xl0, xl1, xl2;
            uint32_t* RT = p.RTg + (size_t)b * 16 * KP2 + t;
            if (t < KKk) {
                const float c0 = xpS[t * 3 + 0];
                const float c1 = xpS[t * 3 + 1];
                const float c2 = xpS[t * 3 + 2];
                xl0 = c0 * Wl[0] + c1 * Wl[3] + c2 * Wl[6] + Bl0;
                xl1 = c0 * Wl[1] + c1 * Wl[4] + c2 * Wl[7] + Bl1;
                xl2 = c0 * Wl[2] + c1 * Wl[5] + c2 * Wl[8] + Bl2;
                const uint4* rr = (const uint4*)(p.Rb + (size_t)(b * NPn + kidx[t]) * 16);
                const uint4 r0 = rr[0], r1 = rr[1], r2 = rr[2], r3 = rr[3];
                RT[ 0 * KP2] = r0.x; RT[ 1 * KP2] = r0.y; RT[ 2 * KP2] = r0.z; RT[ 3 * KP2] = r0.w;
                RT[ 4 * KP2] = r1.x; RT[ 5 * KP2] = r1.y; RT[ 6 * KP2] = r1.z; RT[ 7 * KP2] = r1.w;
                RT[ 8 * KP2] = r2.x; RT[ 9 * KP2] = r2.y; RT[10 * KP2] = r2.z; RT[11 * KP2] = r2.w;
                RT[12 * KP2] = r3.x; RT[13 * KP2] = r3.y; RT[14 * KP2] = r3.z; RT[15 * KP2] = r3.w;
            } else {
                xl0 = 0.0f; xl1 = 0.0f; xl2 = 0.0f;
#pragma unroll
                for (int w = 0; w < 16; ++w) RT[w * KP2] = 0u;
            }
            p.xlg[(size_t)(b * KP2 + t)] = make_float4(xl0, xl1, xl2, 0.0f);
        }
    }
    r21_gridbar(p.bar + 4 * BARSTRIDE);

    // ---- phase 5: GAT (all blocks; grid-stride, one wave per row) ----
    {
        const int wvg = blk * 8 + wv;              // 0..1535
        float Wr[9];
#pragma unroll
        for (int k = 0; k < 9; ++k) Wr[k] = p.gwr[k];
        const float Br0 = p.gbr[0], Br1 = p.gbr[1], Br2 = p.gbr[2];
        const float At0 = p.gatt[0], At1 = p.gatt[1], At2 = p.gatt[2];
        const float Gb0 = p.gbias[0], Gb1 = p.gbias[1], Gb2 = p.gbias[2];

        for (int r = wvg; r < BB * KPAD; r += NWAVE) {
            const int b = r / KPAD, i = r - b * KPAD;
            if (i >= KKk) continue;
            const int bi = p.kidxg[b * KPAD + i];
            const float c0 = p.xpg[(size_t)(b * KPAD + i) * 3 + 0];
            const float c1 = p.xpg[(size_t)(b * KPAD + i) * 3 + 1];
            const float c2 = p.xpg[(size_t)(b * KPAD + i) * 3 + 2];
            const float xr0 = c0 * Wr[0] + c1 * Wr[3] + c2 * Wr[6] + Br0;
            const float xr1 = c0 * Wr[1] + c1 * Wr[4] + c2 * Wr[7] + Br1;
            const float xr2 = c0 * Wr[2] + c1 * Wr[5] + c2 * Wr[8] + Br2;

            const uint32_t mbit = 1u << (bi & 31);
            const uint32_t* Rw = p.RTg + (size_t)(b * 16 + (bi >> 5)) * KP2;
            const float4* xlb = p.xlg + (size_t)b * KP2;

            float mx = -3e38f, lsum = 0.0f, b0 = 0.0f, b1 = 0.0f, b2 = 0.0f;
#pragma unroll
            for (int it = 0; it < 7; ++it) {
                const int j = lane + it * 64;          // < 448, coalesced
                const uint32_t rw = Rw[j];
                const float4 xlv = xlb[j];
                const float xl0 = xlv.x, xl1 = xlv.y, xl2 = xlv.z;
                const bool valid = (rw & mbit) || (j == i);   // pads auto-invalid
                float e0 = xr0 + xl0; e0 = e0 > 0.0f ? e0 : 0.2f * e0;
                float e1 = xr1 + xl1; e1 = e1 > 0.0f ? e1 : 0.2f * e1;
                float e2 = xr2 + xl2; e2 = e2 > 0.0f ? e2 : 0.2f * e2;
                const float sv = At0 * e0 + At1 * e1 + At2 * e2;
                if (valid) {
                    if (sv > mx) {
                        const float rr = __expf(mx - sv);
                        lsum *= rr; b0 *= rr; b1 *= rr; b2 *= rr;
                        mx = sv;
                    }
                    const float pj = __expf(sv - mx);
                    lsum += pj;
                    b0 += pj * xl0; b1 += pj * xl1; b2 += pj * xl2;
                }
            }
#pragma unroll
            for (int off = 32; off; off >>= 1) {       // butterfly LSE merge
                const float mo = __shfl_xor(mx, off);
                const float lo = __shfl_xor(lsum, off);
                const float d0 = __shfl_xor(b0, off);
                const float d1 = __shfl_xor(b1, off);
                const float d2 = __shfl_xor(b2, off);
                const float M  = fmaxf(mx, mo);
                const float ea = __expf(mx - M), eb = __expf(mo - M);
                lsum = lsum * ea + lo * eb;
                b0 = b0 * ea + d0 * eb;
                b1 = b1 * ea + d1 * eb;
                b2 = b2 * ea + d2 * eb;
                mx = M;
            }
            if (lane == 0) {
                const float rl = 1.0f / fmaxf(lsum, 1e-30f);
                p.g_raw[(size_t)(b * KPAD + i) * 3 + 0] = r17_sane(b0 * rl + Gb0);
                p.g_raw[(size_t)(b * KPAD + i) * 3 + 1] = r17_sane(b1 * rl + Gb1);
                p.g_raw[(size_t)(b * KPAD + i) * 3 + 2] = r17_sane(b2 * rl + Gb2);
            }
        }
    }
    r21_gridbar(p.bar + 5 * BARSTRIDE);

    // ---- phase 6: head (blocks 0..15 only; r17_head verbatim, LDS carved) ----
    if (blk < BB) {
        const int b = blk;
        float* sm     = (float*)sbuf;
        float* wred   = sm;          // 24
        float* mv     = sm + 24;     // 6
        float* gp     = sm + 30;     // 3
        float* feat   = sm + 33;     // 19
        float* h1a    = sm + 52;     // 10
        float* h1v    = sm + 62;     // 10
        float* h2a    = sm + 72;     // 5
        float* h2v    = sm + 77;     // 5
        float* a3     = sm + 82;     // 50
        float* vout_s = sm + 132;    // 1
        float* amean_s= sm + 133;    // 1
        const float denom = 1.0f / (float)(BB * KKk);

        float gv0[13], gv1[13], gv2[13];
        float p0 = 0.0f, p1 = 0.0f, p2 = 0.0f;
#pragma unroll
        for (int k = 0; k < 13; ++k) {
            const int r = k * 512 + t;
            float q0 = 0.0f, q1 = 0.0f, q2 = 0.0f;
            if (r < BB * KKk) {
                const int bq = r / KKk, iq = r - bq * KKk;
                const float* gr = p.g_raw + (size_t)(bq * KPAD + iq) * 3;
                q0 = gr[0]; q1 = gr[1]; q2 = gr[2];
            }
            gv0[k] = q0; gv1[k] = q1; gv2[k] = q2;
            p0 += q0; p1 += q1; p2 += q2;
        }
#pragma unroll
        for (int off = 32; off; off >>= 1) {
            p0 += __shfl_xor(p0, off); p1 += __shfl_xor(p1, off); p2 += __shfl_xor(p2, off);
        }
        if (lane == 0) { wred[wv * 3 + 0] = p0; wred[wv * 3 + 1] = p1; wred[wv * 3 + 2] = p2; }
        __syncthreads();
        if (t < 3) {
            float s = 0.0f;
            for (int w = 0; w < 8; ++w) s += wred[w * 3 + t];
            mv[t] = s * denom;
        }
        __syncthreads();
        const float mm0 = p.n2ms[0] * mv[0], mm1 = p.n2ms[1] * mv[1], mm2 = p.n2ms[2] * mv[2];
        float q0a = 0.0f, q1a = 0.0f, q2a = 0.0f;
#pragma unroll
        for (int k = 0; k < 13; ++k) {
            const int r = k * 512 + t;
            if (r < BB * KKk) {
                const float d0 = gv0[k] - mm0, d1 = gv1[k] - mm1, d2 = gv2[k] - mm2;
                q0a += d0 * d0; q1a += d1 * d1; q2a += d2 * d2;
            }
        }
#pragma unroll
        for (int off = 32; off; off >>= 1) {
            q0a += __shfl_xor(q0a, off); q1a += __shfl_xor(q1a, off); q2a += __shfl_xor(q2a, off);
        }
        if (lane == 0) { wred[wv * 3 + 0] = q0a; wred[wv * 3 + 1] = q1a; wred[wv * 3 + 2] = q2a; }
        __syncthreads();
        if (t < 3) {
            float s = 0.0f;
            for (int w = 0; w < 8; ++w) s += wred[w * 3 + t];
            mv[3 + t] = s * denom;
        }
        __syncthreads();

        const float mmv[3] = { mm0, mm1, mm2 };
        float s3[3] = { 0.0f, 0.0f, 0.0f };
        if (t < KKk) {
            const size_t r = (size_t)(b * KPAD + t) * 3;
#pragma unroll
            for (int c = 0; c < 3; ++c) {
                const float iv = 1.0f / sqrtf(fmaxf(mv[3 + c], 0.0f) + EPSf);
                s3[c] = fmaxf((p.g_raw[r + c] - mmv[c]) * iv * p.n2w[c] + p.n2b[c], 0.0f);
            }
        }
        float g0 = s3[0], g1 = s3[1], g2 = s3[2];
#pragma unroll
        for (int off = 32; off; off >>= 1) {
            g0 += __shfl_xor(g0, off); g1 += __shfl_xor(g1, off); g2 += __shfl_xor(g2, off);
        }
        if (lane == 0) { wred[wv * 3 + 0] = g0; wred[wv * 3 + 1] = g1; wred[wv * 3 + 2] = g2; }
        __syncthreads();
        if (t < 3) {
            float s = 0.0f;
            for (int w = 0; w < 8; ++w) s += wred[w * 3 + t];
            gp[t] = s;
        }
        __syncthreads();

        if (t < 19) {
            const int gidx = p.cnid[b] + b * KKk;      // faithful: pooled-K offsets
            float fv;
            if (t < 13)      fv = p.x[(size_t)gidx * NFf + t];
            else if (t < 16) fv = p.x1[(size_t)gidx * 3 + (t - 13)];
            else             fv = gp[t - 16];
            feat[t] = fv;
        }
        __syncthreads();

        if (t < 10) {
            float s = p.a1b[t];
            for (int f = 0; f < 19; ++f) s += feat[f] * p.a1w[f * 10 + t];
            h1a[t] = fmaxf(s, 0.0f);
        } else if (t >= 64 && t < 74) {
            const int j = t - 64;
            float s = p.v1b[j];
            for (int f = 0; f < 19; ++f) s += feat[f] * p.v1w[f * 10 + j];
            h1v[j] = fmaxf(s, 0.0f);
        }
        __syncthreads();
        if (t < 5) {
            float s = p.a2b[t];
            for (int k = 0; k < 10; ++k) s += h1a[k] * p.a2w[k * 5 + t];
            h2a[t] = fmaxf(s, 0.0f);
        } else if (t >= 64 && t < 69) {
            const int j = t - 64;
            float s = p.v2b[j];
            for (int k = 0; k < 10; ++k) s += h1v[k] * p.v2w[k * 5 + j];
            h2v[j] = fmaxf(s, 0.0f);
        }
        __syncthreads();
        if (t < 50) {
            float s = p.a3b[t];
            for (int k = 0; k < 5; ++k) s += h2a[k] * p.a3w[k * 50 + t];
            a3[t] = s;
        } else if (t == 64) {
            float s = p.v3b[0];
            for (int k = 0; k < 5; ++k) s += h2v[k] * p.v3w[k];
            *vout_s = s;
        }
        __syncthreads();
        if (t == 0) {
            float s = 0.0f;
            for (int k = 0; k < 50; ++k) s += a3[k];
            *amean_s = s * (1.0f / 50.0f);
        }
        __syncthreads();
        if (t < 50) {
            float q = *vout_s + a3[t] - *amean_s;
            if (!(q == q)) q = 0.0f;
            q = fminf(fmaxf(q, -QCLMP), QCLMP);
            p.out[b * NAa + t] = (p.amask[b * NAa + t] == 0) ? -1e8f : q;   // FP32
        }
    }
}

// ---------------------------------------------------------------------------
extern "C" void kernel_launch(void* const* d_in, const int* in_sizes, int n_in,
                              void* d_out, int out_size, void* d_ws, size_t ws_size,
                              hipStream_t stream) {
    (void)in_sizes; (void)n_in; (void)out_size;
    R20P p;
    p.x     = (const float*)d_in[0];
    p.ei    = (const int*)d_in[1];
    p.cnid  = (const int*)d_in[4];
    p.amask = (const int*)d_in[5];
    p.panw  = (const float*)d_in[6];
    p.l1w   = (const float*)d_in[7];
    p.l1b   = (const float*)d_in[8];
    p.n1w   = (const float*)d_in[9];
    p.n1b   = (const float*)d_in[10];
    p.n1ms  = (const float*)d_in[11];
    p.poolp = (const float*)d_in[12];
    p.poolb = (const float*)d_in[13];
    p.gwl   = (const float*)d_in[14];
    p.gbl   = (const float*)d_in[15];
    p.gwr   = (const float*)d_in[16];
    p.gbr   = (const float*)d_in[17];
    p.gatt  = (const float*)d_in[18];
    p.gbias = (const float*)d_in[19];
    p.n2w   = (const float*)d_in[20];
    p.n2b   = (const float*)d_in[21];
    p.n2ms  = (const float*)d_in[22];
    p.v1w   = (const float*)d_in[23];
    p.v1b   = (const float*)d_in[24];
    p.v2w   = (const float*)d_in[25];
    p.v2b   = (const float*)d_in[26];
    p.v3w   = (const float*)d_in[27];
    p.v3b   = (const float*)d_in[28];
    p.a1w   = (const float*)d_in[29];
    p.a1b   = (const float*)d_in[30];
    p.a2w   = (const float*)d_in[31];
    p.a2b   = (const float*)d_in[32];
    p.a3w   = (const float*)d_in[33];
    p.a3b   = (const float*)d_in[34];
    p.out   = (float*)d_out;

    // ws layout (bytes): fwdb 512K @0 | trsb 512K @512K | bar 512B @1M |
    //   Rb 512K | csrF | csrT | h_raw | x1 | colsum | g_raw | xpg | xlg(f4) |
    //   kidxg | RTg
    uint8_t* wsb = (uint8_t*)d_ws;
    p.fwdb = (uint32_t*)wsb;
    p.trsb = (uint32_t*)(wsb + 524288);
    p.bar  = (uint32_t*)(wsb + 1048576);
    p.Rb   = (uint32_t*)(wsb + 1049088);
    p.csrF = (unsigned short*)(wsb + 1049088 + 524288);
    p.csrT = p.csrF + (size_t)MAXD * 8192;
    p.h_raw  = (float*)(p.csrT + (size_t)MAXD * 8192);
    p.x1     = p.h_raw + (size_t)NNt * 3;
    p.colsum = p.x1 + (size_t)NNt * 3;
    p.g_raw  = p.colsum + NNt;
    p.xpg    = p.g_raw + (size_t)BB * KPAD * 3;
    p.xlg    = (float4*)(p.xpg + (size_t)BB * KPAD * 3);
    p.kidxg  = (int*)(p.xlg + (size_t)BB * KP2);
    p.RTg    = (uint32_t*)(p.kidxg + (size_t)BB * KPAD);
    const size_t needed = (size_t)((uint8_t*)(p.RTg + (size_t)BB * 16 * KP2) - wsb);
    if (ws_size < needed) return;

    hipMemsetAsync(p.bar, 0, 512, stream);               // one-shot barriers
    r21_mega<<<dim3(NBLK), dim3(512), 0, stream>>>(p);
}

// Round 5
// 265.757 us; speedup vs baseline: 1.3177x; 1.0687x over previous
//
#include <hip/hip_runtime.h>
#include <stdint.h>
#include <math.h>

// PANConcDQL round 22 -- math identical to r19/r21 (passed, absmax 0.0).
// r20/r21 lesson: fused mega pays ~15us per grid barrier (6 barriers) ->
// fusion loses to split. Model: total = fill 40 + fixed ~60 + ~5/dispatch +
// kernel time. So: keep split kernels, CUT DISPATCHES. This round: fold
// memset+scatter+extract INTO mid -- each block scans the edge list (393KB,
// L2-resident) into a per-graph LDS bitset (32KB), extracts an LDS CSR
// (identical dedup + ascending order), loads neighbor regs, then runs the
// r19 propagation verbatim. Dispatches 8 -> 5; global bitset/CSR gone.
#define BB   16
#define NPn  512
#define LLp  20
#define NAa  50
#define KKk  410
#define NNt  (BB * NPn)   // 8192
#define EEe  (6 * NNt)    // 49152
#define NFf  13
#define KPAD 416
#define KP2  448          // padded GAT staging width (7*64)
#define EPSf 1e-5f
#define QCLMP 1e6f
#define MAXD 28
#define PADR 512

__device__ __forceinline__ float r17_sane(float v) {
    if (!(v == v)) return 0.0f;
    return fminf(fmaxf(v, -1e15f), 1e15f);
}

// wave-max of per-thread real degree (pads are PADR).
__device__ __forceinline__ int r19_wmaxdeg(const int (&iF)[MAXD]) {
    int deg = 0;
#pragma unroll
    for (int j = 0; j < MAXD; ++j) deg += (iF[j] != PADR) ? 1 : 0;
#pragma unroll
    for (int off = 32; off; off >>= 1) {
        const int o = __shfl_xor(deg, off);
        deg = o > deg ? o : deg;
    }
    return deg;
}

// chunked gather-sum: compile-time indices only; dm is wave-uniform.
__device__ __forceinline__ float r19_gsum(const float* __restrict__ rp,
                                          const int (&iF)[MAXD], int dm) {
    float s = 0.0f;
    s += rp[iF[0]]; s += rp[iF[1]]; s += rp[iF[2]]; s += rp[iF[3]];
    if (dm > 4) {
        s += rp[iF[4]]; s += rp[iF[5]]; s += rp[iF[6]]; s += rp[iF[7]];
        if (dm > 8) {
            s += rp[iF[8]]; s += rp[iF[9]]; s += rp[iF[10]]; s += rp[iF[11]];
            if (dm > 12) {
                s += rp[iF[12]]; s += rp[iF[13]]; s += rp[iF[14]]; s += rp[iF[15]];
                if (dm > 16) {
                    s += rp[iF[16]]; s += rp[iF[17]]; s += rp[iF[18]]; s += rp[iF[19]];
                    if (dm > 20) {
                        s += rp[iF[20]]; s += rp[iF[21]]; s += rp[iF[22]]; s += rp[iF[23]];
                        if (dm > 24) {
                            s += rp[iF[24]]; s += rp[iF[25]]; s += rp[iF[26]]; s += rp[iF[27]];
                        }
                    }
                }
            }
        }
    }
    return s;
}

// chunked gather-OR over uint2 planes (b64 reads).
__device__ __forceinline__ void r19_gor(const uint2* __restrict__ rp,
                                        const int (&iF)[MAXD], int dm, uint2& r) {
    {
        const uint2 v0 = rp[iF[0]], v1 = rp[iF[1]], v2 = rp[iF[2]], v3 = rp[iF[3]];
        r.x |= v0.x | v1.x | v2.x | v3.x;
        r.y |= v0.y | v1.y | v2.y | v3.y;
    }
    if (dm > 4) {
        const uint2 v0 = rp[iF[4]], v1 = rp[iF[5]], v2 = rp[iF[6]], v3 = rp[iF[7]];
        r.x |= v0.x | v1.x | v2.x | v3.x;
        r.y |= v0.y | v1.y | v2.y | v3.y;
        if (dm > 8) {
            const uint2 w0 = rp[iF[8]], w1 = rp[iF[9]], w2 = rp[iF[10]], w3 = rp[iF[11]];
            r.x |= w0.x | w1.x | w2.x | w3.x;
            r.y |= w0.y | w1.y | w2.y | w3.y;
            if (dm > 12) {
                const uint2 u0 = rp[iF[12]], u1 = rp[iF[13]], u2 = rp[iF[14]], u3 = rp[iF[15]];
                r.x |= u0.x | u1.x | u2.x | u3.x;
                r.y |= u0.y | u1.y | u2.y | u3.y;
                if (dm > 16) {
                    const uint2 a0 = rp[iF[16]], a1 = rp[iF[17]], a2 = rp[iF[18]], a3 = rp[iF[19]];
                    r.x |= a0.x | a1.x | a2.x | a3.x;
                    r.y |= a0.y | a1.y | a2.y | a3.y;
                    if (dm > 20) {
                        const uint2 b0 = rp[iF[20]], b1 = rp[iF[21]], b2 = rp[iF[22]], b3 = rp[iF[23]];
                        r.x |= b0.x | b1.x | b2.x | b3.x;
                        r.y |= b0.y | b1.y | b2.y | b3.y;
                        if (dm > 24) {
                            const uint2 c0 = rp[iF[24]], c1 = rp[iF[25]], c2 = rp[iF[26]], c3 = rp[iF[27]];
                            r.x |= c0.x | c1.x | c2.x | c3.x;
                            r.y |= c0.y | c1.y | c2.y | c3.y;
                        }
                    }
                }
            }
        }
    }
}

// build one adjacency direction for graph b into LDS: zero bitset A, scan
// edges (fwd: rows=dst, bits=src; trs: rows=src, bits=dst), extract CSR to
// LDS C (u16 [MAXD][512], identical dedup + ascending order as r17_extract),
// then the caller loads registers from C with compile-time j.
__device__ __forceinline__ void r22_build(
    uint32_t* __restrict__ A, unsigned short* __restrict__ C,
    const int* __restrict__ ei, int b, int t, bool trs)
{
#pragma unroll
    for (int k = 0; k < 16; ++k) A[k * 512 + t] = 0u;   // zero 32KB coalesced
    __syncthreads();
    for (int k = 0; k < EEe / 512; ++k) {               // 96 coalesced iters
        const int e = k * 512 + t;
        const int src = ei[e], dst = ei[EEe + e];
        if (!trs) {
            if ((dst >> 9) == b)
                atomicOr(&A[(dst & 511) * 16 + ((src & 511) >> 5)], 1u << (src & 31));
        } else {
            if ((src >> 9) == b)
                atomicOr(&A[(src & 511) * 16 + ((dst & 511) >> 5)], 1u << (dst & 31));
        }
    }
    __syncthreads();
    int cnt = 0;                                        // extract row t
    for (int w = 0; w < 16; ++w) {
        uint32_t bits = A[t * 16 + w];
        while (bits) {
            const int u = (w << 5) + __ffs(bits) - 1;
            bits &= bits - 1;
            if (cnt < MAXD) C[cnt * 512 + t] = (unsigned short)u;
            ++cnt;
        }
    }
    for (int j = cnt; j < MAXD; ++j) C[j * 512 + t] = PADR;
    __syncthreads();
}

// ---------------------------------------------------------------------------
// K1: mid with in-LDS adjacency build. grid (16,12) x 512.
// y<4: channel planes (c=0..2) + colsum (c=3, needs transpose adjacency);
// y in 4..11: reachability plane pairs (uint2).
__global__ __launch_bounds__(512) void r22_mid(
    const float* __restrict__ x,
    const int* __restrict__ ei,
    const float* __restrict__ panw,
    const float* __restrict__ l1w, const float* __restrict__ l1b,
    float* __restrict__ h_raw, float* __restrict__ colsum,
    uint32_t* __restrict__ Rb)
{
    // region A: bitset 8192 u32 (32KB). region B: CSR u16[28][512] (28KB),
    // later reused for pa/pb/wsh (or R1/R2). 61.7KB total.
    __shared__ __align__(16) uint32_t S[8192 + 7168];
    uint32_t* A = S;
    unsigned short* C = (unsigned short*)(S + 8192);
    const int b = blockIdx.x, y = blockIdx.y, t = threadIdx.x;
    const int node = b * 512 + t;

    r22_build(A, C, ei, b, t, false);                   // forward adjacency
    int iF[MAXD];
#pragma unroll
    for (int j = 0; j < MAXD; ++j) iF[j] = (int)C[j * 512 + t];
    const int dmF = r19_wmaxdeg(iF);

    int idx[MAXD];
    int dm2;
    if (y == 3) {                                       // colsum: transpose
        __syncthreads();                                // all iF loads done
        r22_build(A, C, ei, b, t, true);
#pragma unroll
        for (int j = 0; j < MAXD; ++j) idx[j] = (int)C[j * 512 + t];
        dm2 = r19_wmaxdeg(idx);
    } else {
#pragma unroll
        for (int j = 0; j < MAXD; ++j) idx[j] = iF[j];
        dm2 = dmF;
    }
    __syncthreads();                                    // C reads done; B reusable

    if (y < 4) {
        const int c = y;
        float* pa  = (float*)(S + 8192);       // 513
        float* pb  = pa + 513;                 // 513
        float* wsh = pb + 513;                 // 21
        if (t < 21) wsh[t] = panw[t];

        pa[t] = 1.0f;
        if (t == 0) { pa[512] = 0.0f; pb[512] = 0.0f; }
        __syncthreads();
        float dacc = wsh[0];
        {
            float* rp = pa; float* rn = pb;
            for (int i = 1; i <= LLp; ++i) {
                const float s = r19_gsum(rp, iF, dmF);
                rn[t] = s;
                dacc += wsh[i] * s;
                __syncthreads();
                float* tp = rp; rp = rn; rn = tp;
            }
        }
        const float d0 = (dacc > 0.0f) ? 1.0f / sqrtf(dacc) : 0.0f;

        float seed;
        if (c < 3) {
            float xw = 0.0f;
            const float* xr = x + (size_t)node * NFf;
            for (int f = 0; f < NFf; ++f) xw += xr[f] * l1w[f * 3 + c];
            seed = d0 * xw;
        } else {
            seed = d0;
        }
        pa[t] = seed;
        if (t == 0) { pa[512] = 0.0f; pb[512] = 0.0f; }
        __syncthreads();
        float acc = wsh[0] * seed;
        {
            float* rp = pa; float* rn = pb;
            for (int i = 1; i <= LLp; ++i) {
                const float s = r19_gsum(rp, idx, dm2);
                rn[t] = s;
                acc += wsh[i] * s;
                __syncthreads();
                float* tp = rp; rp = rn; rn = tp;
            }
        }
        if (c < 3) h_raw[(size_t)node * 3 + c] = r17_sane(d0 * acc + l1b[c]);
        else       colsum[node] = r17_sane(d0 * acc);
    } else {
        const int q = y - 4;                   // plane pair {2q, 2q+1}
        uint2* R1 = (uint2*)(S + 8192);        // 513
        uint2* R2 = R1 + 513;                  // 513
        uint2 seed;
        seed.x = ((t >> 5) == 2 * q)     ? (1u << (t & 31)) : 0u;
        seed.y = ((t >> 5) == 2 * q + 1) ? (1u << (t & 31)) : 0u;
        R1[t] = seed;
        if (t == 0) {
            uint2 z; z.x = 0u; z.y = 0u;
            R1[512] = z; R2[512] = z;
        }
        __syncthreads();
        uint2* Rp = R1; uint2* Rn = R2;
        for (int i = 0; i < LLp; ++i) {
            uint2 r = Rp[t];
            r19_gor(Rp, iF, dmF, r);
            Rn[t] = r;
            __syncthreads();
            uint2* tp = Rp; Rp = Rn; Rn = tp;
        }
        *(uint2*)(&Rb[(size_t)node * 16 + 2 * q]) = Rp[t];
    }
}

// ---------------------------------------------------------------------------
// K2: pool -- grid 16 x 512 (r19_pool verbatim).
__global__ __launch_bounds__(512) void r19_pool(
    const float* __restrict__ h_raw,
    const float* __restrict__ colsum,
    const uint32_t* __restrict__ Rb,
    const float* n1w, const float* n1b, const float* n1ms,
    const float* poolp, const float* poolb,
    const float* gwl, const float* gbl,
    float* __restrict__ x1,
    float* __restrict__ xpg,      // [BB][KPAD][3]
    float4* __restrict__ xlg,     // [BB][KP2]  (pads zeroed)
    int*   __restrict__ kidxg,    // [BB][KPAD]
    uint32_t* __restrict__ RTg)   // [BB][16][KP2] (pads zeroed)
{
    __shared__ __align__(16) uint32_t pg[2208];
    float* sc   = (float*)pg;                  // 512
    float* mv   = (float*)(pg + 512);          // 8
    float* wred = (float*)(pg + 520);          // 24
    float* xpS  = (float*)(pg + 544);          // 1248 (416*3)
    int*   kidx = (int*)(pg + 1792);           // 416
    const int b = blockIdx.x, t = threadIdx.x;
    const int lane = t & 63, wv = t >> 6;
    const float inv_n = 1.0f / (float)NNt;

    float hv0[16], hv1[16], hv2[16];
    float p0 = 0.0f, p1 = 0.0f, p2 = 0.0f;
#pragma unroll
    for (int k = 0; k < 16; ++k) {
        const float* hr = h_raw + (size_t)(k * 512 + t) * 3;
        hv0[k] = hr[0]; hv1[k] = hr[1]; hv2[k] = hr[2];
        p0 += hv0[k]; p1 += hv1[k]; p2 += hv2[k];
    }
#pragma unroll
    for (int off = 32; off; off >>= 1) {
        p0 += __shfl_xor(p0, off); p1 += __shfl_xor(p1, off); p2 += __shfl_xor(p2, off);
    }
    if (lane == 0) { wred[wv * 3 + 0] = p0; wred[wv * 3 + 1] = p1; wred[wv * 3 + 2] = p2; }
    __syncthreads();
    if (t < 3) {
        float s = 0.0f;
        for (int w = 0; w < 8; ++w) s += wred[w * 3 + t];
        mv[t] = s * inv_n;
    }
    __syncthreads();
    const float mm0 = n1ms[0] * mv[0], mm1 = n1ms[1] * mv[1], mm2 = n1ms[2] * mv[2];
    float q0 = 0.0f, q1 = 0.0f, q2 = 0.0f;
#pragma unroll
    for (int k = 0; k < 16; ++k) {
        const float d0 = hv0[k] - mm0, d1 = hv1[k] - mm1, d2 = hv2[k] - mm2;
        q0 += d0 * d0; q1 += d1 * d1; q2 += d2 * d2;
    }
#pragma unroll
    for (int off = 32; off; off >>= 1) {
        q0 += __shfl_xor(q0, off); q1 += __shfl_xor(q1, off); q2 += __shfl_xor(q2, off);
    }
    if (lane == 0) { wred[wv * 3 + 0] = q0; wred[wv * 3 + 1] = q1; wred[wv * 3 + 2] = q2; }
    __syncthreads();
    if (t < 3) {
        float s = 0.0f;
        for (int w = 0; w < 8; ++w) s += wred[w * 3 + t];
        mv[3 + t] = s * inv_n;
    }
    __syncthreads();

    const float mmv[3] = { mm0, mm1, mm2 };
    float xv[3];
#pragma unroll
    for (int c = 0; c < 3; ++c) {
        const float iv = 1.0f / sqrtf(fmaxf(mv[3 + c], 0.0f) + EPSf);
        const float o  = h_raw[(size_t)(b * NPn + t) * 3 + c] - mmv[c];
        const float tt = n1w[c] * o * iv + n1b[c];
        xv[c] = fmaxf(tt, 0.0f);
        x1[(size_t)(b * NPn + t) * 3 + c] = xv[c];
    }
    float s = poolb[0] * (xv[0] * poolp[0] + xv[1] * poolp[1] + xv[2] * poolp[2])
            + poolb[1] * colsum[b * NPn + t];
    s = tanhf(s);
    if (!(s == s)) s = 0.0f;
    sc[t] = s;
    __syncthreads();

    int cnt = 0;
    for (int u = 0; u < NPn; u += 4) {
        const float4 s4 = *(const float4*)(sc + u);
        cnt += ((s4.x > s) || (s4.x == s && (u + 0) < t)) ? 1 : 0;
        cnt += ((s4.y > s) || (s4.y == s && (u + 1) < t)) ? 1 : 0;
        cnt += ((s4.z > s) || (s4.z == s && (u + 2) < t)) ? 1 : 0;
        cnt += ((s4.w > s) || (s4.w == s && (u + 3) < t)) ? 1 : 0;
    }
    if (cnt < KKk) {                       // rank-count bijection
        const float xp0 = xv[0] * s, xp1 = xv[1] * s, xp2 = xv[2] * s;
        kidx[cnt] = t;
        xpS[cnt * 3 + 0] = xp0;
        xpS[cnt * 3 + 1] = xp1;
        xpS[cnt * 3 + 2] = xp2;
        kidxg[b * KPAD + cnt] = t;
        xpg[(size_t)(b * KPAD + cnt) * 3 + 0] = xp0;
        xpg[(size_t)(b * KPAD + cnt) * 3 + 1] = xp1;
        xpg[(size_t)(b * KPAD + cnt) * 3 + 2] = xp2;
    }
    __syncthreads();

    float Wl[9];
#pragma unroll
    for (int i2 = 0; i2 < 9; ++i2) Wl[i2] = gwl[i2];
    const float Bl0 = gbl[0], Bl1 = gbl[1], Bl2 = gbl[2];
    if (t < KP2) {
        float xl0, xl1, xl2;
        uint32_t* RT = RTg + (size_t)b * 16 * KP2 + t;
        if (t < KKk) {
            const float c0 = xpS[t * 3 + 0];
            const float c1 = xpS[t * 3 + 1];
            const float c2 = xpS[t * 3 + 2];
            xl0 = c0 * Wl[0] + c1 * Wl[3] + c2 * Wl[6] + Bl0;
            xl1 = c0 * Wl[1] + c1 * Wl[4] + c2 * Wl[7] + Bl1;
            xl2 = c0 * Wl[2] + c1 * Wl[5] + c2 * Wl[8] + Bl2;
            const uint4* rr = (const uint4*)(Rb + (size_t)(b * NPn + kidx[t]) * 16);
            const uint4 r0 = rr[0], r1 = rr[1], r2 = rr[2], r3 = rr[3];
            RT[ 0 * KP2] = r0.x; RT[ 1 * KP2] = r0.y; RT[ 2 * KP2] = r0.z; RT[ 3 * KP2] = r0.w;
            RT[ 4 * KP2] = r1.x; RT[ 5 * KP2] = r1.y; RT[ 6 * KP2] = r1.z; RT[ 7 * KP2] = r1.w;
            RT[ 8 * KP2] = r2.x; RT[ 9 * KP2] = r2.y; RT[10 * KP2] = r2.z; RT[11 * KP2] = r2.w;
            RT[12 * KP2] = r3.x; RT[13 * KP2] = r3.y; RT[14 * KP2] = r3.z; RT[15 * KP2] = r3.w;
        } else {
            xl0 = 0.0f; xl1 = 0.0f; xl2 = 0.0f;
#pragma unroll
            for (int w = 0; w < 16; ++w) RT[w * KP2] = 0u;
        }
        xlg[(size_t)(b * KP2 + t)] = make_float4(xl0, xl1, xl2, 0.0f);
    }
}

// ---------------------------------------------------------------------------
// K3: GAT -- grid (16,52) x 512, one wave per output row, no LDS (r19 verbatim).
__global__ __launch_bounds__(512) void r19_gat(
    const float* __restrict__ xpg,
    const float4* __restrict__ xlg,
    const int* __restrict__ kidxg,
    const uint32_t* __restrict__ RTg,
    const float* __restrict__ gwr, const float* __restrict__ gbr,
    const float* __restrict__ gatt, const float* __restrict__ gbias,
    float* __restrict__ g_raw)
{
    const int b = blockIdx.x, y = blockIdx.y, t = threadIdx.x;
    const int lane = t & 63, wv = t >> 6;
    const int i = y * 8 + wv;                  // row of this wave
    if (i >= KKk) return;

    float Wr[9];
#pragma unroll
    for (int k = 0; k < 9; ++k) Wr[k] = gwr[k];
    const float Br0 = gbr[0], Br1 = gbr[1], Br2 = gbr[2];
    const float At0 = gatt[0], At1 = gatt[1], At2 = gatt[2];
    const float Gb0 = gbias[0], Gb1 = gbias[1], Gb2 = gbias[2];

    const int bi = kidxg[b * KPAD + i];
    const float c0 = xpg[(size_t)(b * KPAD + i) * 3 + 0];
    const float c1 = xpg[(size_t)(b * KPAD + i) * 3 + 1];
    const float c2 = xpg[(size_t)(b * KPAD + i) * 3 + 2];
    const float xr0 = c0 * Wr[0] + c1 * Wr[3] + c2 * Wr[6] + Br0;
    const float xr1 = c0 * Wr[1] + c1 * Wr[4] + c2 * Wr[7] + Br1;
    const float xr2 = c0 * Wr[2] + c1 * Wr[5] + c2 * Wr[8] + Br2;

    const uint32_t mbit = 1u << (bi & 31);
    const uint32_t* Rw = RTg + (size_t)(b * 16 + (bi >> 5)) * KP2;
    const float4* xlb = xlg + (size_t)b * KP2;

    float mx = -3e38f, lsum = 0.0f, b0 = 0.0f, b1 = 0.0f, b2 = 0.0f;
#pragma unroll
    for (int it = 0; it < 7; ++it) {
        const int j = lane + it * 64;          // < 448, coalesced
        const uint32_t rw = Rw[j];
        const float4 xlv = xlb[j];
        const float xl0 = xlv.x, xl1 = xlv.y, xl2 = xlv.z;
        const bool valid = (rw & mbit) || (j == i);   // pads auto-invalid
        float e0 = xr0 + xl0; e0 = e0 > 0.0f ? e0 : 0.2f * e0;
        float e1 = xr1 + xl1; e1 = e1 > 0.0f ? e1 : 0.2f * e1;
        float e2 = xr2 + xl2; e2 = e2 > 0.0f ? e2 : 0.2f * e2;
        const float sv = At0 * e0 + At1 * e1 + At2 * e2;
        if (valid) {
            if (sv > mx) {
                const float r = __expf(mx - sv);
                lsum *= r; b0 *= r; b1 *= r; b2 *= r;
                mx = sv;
            }
            const float pj = __expf(sv - mx);
            lsum += pj;
            b0 += pj * xl0; b1 += pj * xl1; b2 += pj * xl2;
        }
    }
#pragma unroll
    for (int off = 32; off; off >>= 1) {       // butterfly LSE merge
        const float mo = __shfl_xor(mx, off);
        const float lo = __shfl_xor(lsum, off);
        const float d0 = __shfl_xor(b0, off);
        const float d1 = __shfl_xor(b1, off);
        const float d2 = __shfl_xor(b2, off);
        const float M  = fmaxf(mx, mo);
        const float ea = __expf(mx - M), eb = __expf(mo - M);
        lsum = lsum * ea + lo * eb;
        b0 = b0 * ea + d0 * eb;
        b1 = b1 * ea + d1 * eb;
        b2 = b2 * ea + d2 * eb;
        mx = M;
    }
    if (lane == 0) {
        const float rl = 1.0f / fmaxf(lsum, 1e-30f);
        g_raw[(size_t)(b * KPAD + i) * 3 + 0] = r17_sane(b0 * rl + Gb0);
        g_raw[(size_t)(b * KPAD + i) * 3 + 1] = r17_sane(b1 * rl + Gb1);
        g_raw[(size_t)(b * KPAD + i) * 3 + 2] = r17_sane(b2 * rl + Gb2);
    }
}

// ---------------------------------------------------------------------------
// K4: head (r17_head verbatim).
__global__ __launch_bounds__(512) void r17_head(
    const float* __restrict__ g_raw,
    const float* __restrict__ x1,
    const float* __restrict__ x,
    const int* __restrict__ cnid,
    const int* __restrict__ amask,
    const float* n2w, const float* n2b, const float* n2ms,
    const float* v1w, const float* v1b,
    const float* v2w, const float* v2b,
    const float* v3w, const float* v3b,
    const float* a1w, const float* a1b,
    const float* a2w, const float* a2b,
    const float* a3w, const float* a3b,
    float* __restrict__ out)
{
    __shared__ float wred[24];
    __shared__ float mv[6];
    __shared__ float gp[3];
    __shared__ float feat[19];
    __shared__ float h1a[10], h1v[10], h2a[5], h2v[5];
    __shared__ float a3[50];
    __shared__ float vout_s, amean_s;
    const int b = blockIdx.x, t = threadIdx.x;
    const int lane = t & 63, wv = t >> 6;
    const float denom = 1.0f / (float)(BB * KKk);

    float gv0[13], gv1[13], gv2[13];
    float p0 = 0.0f, p1 = 0.0f, p2 = 0.0f;
#pragma unroll
    for (int k = 0; k < 13; ++k) {
        const int r = k * 512 + t;
        float q0 = 0.0f, q1 = 0.0f, q2 = 0.0f;
        if (r < BB * KKk) {
            const int bq = r / KKk, iq = r - bq * KKk;
            const float* gr = g_raw + (size_t)(bq * KPAD + iq) * 3;
            q0 = gr[0]; q1 = gr[1]; q2 = gr[2];
        }
        gv0[k] = q0; gv1[k] = q1; gv2[k] = q2;
        p0 += q0; p1 += q1; p2 += q2;
    }
#pragma unroll
    for (int off = 32; off; off >>= 1) {
        p0 += __shfl_xor(p0, off); p1 += __shfl_xor(p1, off); p2 += __shfl_xor(p2, off);
    }
    if (lane == 0) { wred[wv * 3 + 0] = p0; wred[wv * 3 + 1] = p1; wred[wv * 3 + 2] = p2; }
    __syncthreads();
    if (t < 3) {
        float s = 0.0f;
        for (int w = 0; w < 8; ++w) s += wred[w * 3 + t];
        mv[t] = s * denom;
    }
    __syncthreads();
    const float mm0 = n2ms[0] * mv[0], mm1 = n2ms[1] * mv[1], mm2 = n2ms[2] * mv[2];
    float q0a = 0.0f, q1a = 0.0f, q2a = 0.0f;
#pragma unroll
    for (int k = 0; k < 13; ++k) {
        const int r = k * 512 + t;
        if (r < BB * KKk) {
            const float d0 = gv0[k] - mm0, d1 = gv1[k] - mm1, d2 = gv2[k] - mm2;
            q0a += d0 * d0; q1a += d1 * d1; q2a += d2 * d2;
        }
    }
#pragma unroll
    for (int off = 32; off; off >>= 1) {
        q0a += __shfl_xor(q0a, off); q1a += __shfl_xor(q1a, off); q2a += __shfl_xor(q2a, off);
    }
    if (lane == 0) { wred[wv * 3 + 0] = q0a; wred[wv * 3 + 1] = q1a; wred[wv * 3 + 2] = q2a; }
    __syncthreads();
    if (t < 3) {
        float s = 0.0f;
        for (int w = 0; w < 8; ++w) s += wred[w * 3 + t];
        mv[3 + t] = s * denom;
    }
    __syncthreads();

    const float mmv[3] = { mm0, mm1, mm2 };
    float s3[3] = { 0.0f, 0.0f, 0.0f };
    if (t < KKk) {
        const size_t r = (size_t)(b * KPAD + t) * 3;
#pragma unroll
        for (int c = 0; c < 3; ++c) {
            const float iv = 1.0f / sqrtf(fmaxf(mv[3 + c], 0.0f) + EPSf);
            s3[c] = fmaxf((g_raw[r + c] - mmv[c]) * iv * n2w[c] + n2b[c], 0.0f);
        }
    }
    float g0 = s3[0], g1 = s3[1], g2 = s3[2];
#pragma unroll
    for (int off = 32; off; off >>= 1) {
        g0 += __shfl_xor(g0, off); g1 += __shfl_xor(g1, off); g2 += __shfl_xor(g2, off);
    }
    if (lane == 0) { wred[wv * 3 + 0] = g0; wred[wv * 3 + 1] = g1; wred[wv * 3 + 2] = g2; }
    __syncthreads();
    if (t < 3) {
        float s = 0.0f;
        for (int w = 0; w < 8; ++w) s += wred[w * 3 + t];
        gp[t] = s;
    }
    __syncthreads();

    if (t < 19) {
        const int gidx = cnid[b] + b * KKk;        // faithful: pooled-K offsets
        float fv;
        if (t < 13)      fv = x[(size_t)gidx * NFf + t];
        else if (t < 16) fv = x1[(size_t)gidx * 3 + (t - 13)];
        else             fv = gp[t - 16];
        feat[t] = fv;
    }
    __syncthreads();

    if (t < 10) {
        float s = a1b[t];
        for (int f = 0; f < 19; ++f) s += feat[f] * a1w[f * 10 + t];
        h1a[t] = fmaxf(s, 0.0f);
    } else if (t >= 64 && t < 74) {
        const int j = t - 64;
        float s = v1b[j];
        for (int f = 0; f < 19; ++f) s += feat[f] * v1w[f * 10 + j];
        h1v[j] = fmaxf(s, 0.0f);
    }
    __syncthreads();
    if (t < 5) {
        float s = a2b[t];
        for (int k = 0; k < 10; ++k) s += h1a[k] * a2w[k * 5 + t];
        h2a[t] = fmaxf(s, 0.0f);
    } else if (t >= 64 && t < 69) {
        const int j = t - 64;
        float s = v2b[j];
        for (int k = 0; k < 10; ++k) s += h1v[k] * v2w[k * 5 + j];
        h2v[j] = fmaxf(s, 0.0f);
    }
    __syncthreads();
    if (t < 50) {
        float s = a3b[t];
        for (int k = 0; k < 5; ++k) s += h2a[k] * a3w[k * 50 + t];
        a3[t] = s;
    } else if (t == 64) {
        float s = v3b[0];
        for (int k = 0; k < 5; ++k) s += h2v[k] * v3w[k];
        vout_s = s;
    }
    __syncthreads();
    if (t == 0) {
        float s = 0.0f;
        for (int k = 0; k < 50; ++k) s += a3[k];
        amean_s = s * (1.0f / 50.0f);
    }
    __syncthreads();
    if (t < 50) {
        float q = vout_s + a3[t] - amean_s;
        if (!(q == q)) q = 0.0f;
        q = fminf(fmaxf(q, -QCLMP), QCLMP);
        out[b * NAa + t] = (amask[b * NAa + t] == 0) ? -1e8f : q;   // FP32
    }
}

// ---------------------------------------------------------------------------
extern "C" void kernel_launch(void* const* d_in, const int* in_sizes, int n_in,
                              void* d_out, int out_size, void* d_ws, size_t ws_size,
                              hipStream_t stream) {
    (void)in_sizes; (void)n_in; (void)out_size;
    const float* x     = (const float*)d_in[0];
    const int* ei      = (const int*)d_in[1];
    const int* cnid    = (const int*)d_in[4];
    const int* amask   = (const int*)d_in[5];
    const float* panw  = (const float*)d_in[6];
    const float* l1w   = (const float*)d_in[7];
    const float* l1b   = (const float*)d_in[8];
    const float* n1w   = (const float*)d_in[9];
    const float* n1b   = (const float*)d_in[10];
    const float* n1ms  = (const float*)d_in[11];
    const float* poolp = (const float*)d_in[12];
    const float* poolb = (const float*)d_in[13];
    const float* gwl   = (const float*)d_in[14];
    const float* gbl   = (const float*)d_in[15];
    const float* gwr   = (const float*)d_in[16];
    const float* gbr   = (const float*)d_in[17];
    const float* gatt  = (const float*)d_in[18];
    const float* gbias = (const float*)d_in[19];
    const float* n2w   = (const float*)d_in[20];
    const float* n2b   = (const float*)d_in[21];
    const float* n2ms  = (const float*)d_in[22];
    const float* v1w   = (const float*)d_in[23];
    const float* v1b   = (const float*)d_in[24];
    const float* v2w   = (const float*)d_in[25];
    const float* v2b   = (const float*)d_in[26];
    const float* v3w   = (const float*)d_in[27];
    const float* v3b   = (const float*)d_in[28];
    const float* a1w   = (const float*)d_in[29];
    const float* a1b   = (const float*)d_in[30];
    const float* a2w   = (const float*)d_in[31];
    const float* a2b   = (const float*)d_in[32];
    const float* a3w   = (const float*)d_in[33];
    const float* a3b   = (const float*)d_in[34];
    float* out         = (float*)d_out;

    // ws layout (floats/u32): Rb 512K | h_raw | x1 | colsum | g_raw | xpg |
    //                         xlg(f4) | kidxg | RTg
    uint8_t* wsb = (uint8_t*)d_ws;
    uint32_t* Rb   = (uint32_t*)wsb;
    float* h_raw  = (float*)(wsb + 524288);
    float* x1     = h_raw + (size_t)NNt * 3;
    float* colsum = x1 + (size_t)NNt * 3;
    float* g_raw  = colsum + NNt;
    float* xpg    = g_raw + (size_t)BB * KPAD * 3;
    float4* xlg   = (float4*)(xpg + (size_t)BB * KPAD * 3);
    int*   kidxg  = (int*)(xlg + (size_t)BB * KP2);
    uint32_t* RTg = (uint32_t*)(kidxg + (size_t)BB * KPAD);
    const size_t needed = (size_t)((uint8_t*)(RTg + (size_t)BB * 16 * KP2) - wsb);
    if (ws_size < needed) return;

    r22_mid<<<dim3(16, 12), dim3(512), 0, stream>>>(x, ei, panw, l1w, l1b,
                                                    h_raw, colsum, Rb);
    r19_pool<<<dim3(16), dim3(512), 0, stream>>>(h_raw, colsum, Rb,
                                                 n1w, n1b, n1ms, poolp, poolb,
                                                 gwl, gbl,
                                                 x1, xpg, xlg, kidxg, RTg);
    r19_gat<<<dim3(16, 52), dim3(512), 0, stream>>>(xpg, xlg, kidxg, RTg,
                                                    gwr, gbr, gatt, gbias, g_raw);
    r17_head<<<dim3(16), dim3(512), 0, stream>>>(g_raw, x1, x, cnid, amask,
                                                 n2w, n2b, n2ms, v1w, v1b, v2w, v2b, v3w, v3b,
                                                 a1w, a1b, a2w, a2b, a3w, a3b, out);
}

// Round 6
// 202.316 us; speedup vs baseline: 1.7310x; 1.3136x over previous
//
#include <hip/hip_runtime.h>
#include <stdint.h>
#include <math.h>

// PANConcDQL round 23 -- math identical to r19 (passed, absmax 0.0).
// r20-r22 lessons: per-dispatch gap ~0 (graph replay), fixed ~80us harness
// overhead, fill 40us floor -> only the ~81us of kernel time is controllable.
// This round: halve mid's serial chain count. The degree chain (seed=ones ->
// d0) is identical across mid's 4 compute blocks and needs only the forward
// adjacency -> compute it ONCE per graph in the extract dispatch (16 extra
// 512-thread blocks reading the edge bitset, identical index order + FP op
// order), store d0g. Mid's y<4 blocks read d0g and run only the seeded
// 20-round chain (mid wall 40 -> 20 rounds). All else r19 verbatim.
#define BB   16
#define NPn  512
#define LLp  20
#define NAa  50
#define KKk  410
#define NNt  (BB * NPn)   // 8192
#define EEe  (6 * NNt)    // 49152
#define NFf  13
#define KPAD 416
#define KP2  448          // padded GAT staging width (7*64)
#define EPSf 1e-5f
#define QCLMP 1e6f
#define MAXD 28
#define PADR 512

__device__ __forceinline__ float r17_sane(float v) {
    if (!(v == v)) return 0.0f;
    return fminf(fmaxf(v, -1e15f), 1e15f);
}

// wave-max of per-thread real degree (pads are PADR).
__device__ __forceinline__ int r19_wmaxdeg(const int (&iF)[MAXD]) {
    int deg = 0;
#pragma unroll
    for (int j = 0; j < MAXD; ++j) deg += (iF[j] != PADR) ? 1 : 0;
#pragma unroll
    for (int off = 32; off; off >>= 1) {
        const int o = __shfl_xor(deg, off);
        deg = o > deg ? o : deg;
    }
    return deg;
}

// chunked gather-sum: compile-time indices only; dm is wave-uniform.
__device__ __forceinline__ float r19_gsum(const float* __restrict__ rp,
                                          const int (&iF)[MAXD], int dm) {
    float s = 0.0f;
    s += rp[iF[0]]; s += rp[iF[1]]; s += rp[iF[2]]; s += rp[iF[3]];
    if (dm > 4) {
        s += rp[iF[4]]; s += rp[iF[5]]; s += rp[iF[6]]; s += rp[iF[7]];
        if (dm > 8) {
            s += rp[iF[8]]; s += rp[iF[9]]; s += rp[iF[10]]; s += rp[iF[11]];
            if (dm > 12) {
                s += rp[iF[12]]; s += rp[iF[13]]; s += rp[iF[14]]; s += rp[iF[15]];
                if (dm > 16) {
                    s += rp[iF[16]]; s += rp[iF[17]]; s += rp[iF[18]]; s += rp[iF[19]];
                    if (dm > 20) {
                        s += rp[iF[20]]; s += rp[iF[21]]; s += rp[iF[22]]; s += rp[iF[23]];
                        if (dm > 24) {
                            s += rp[iF[24]]; s += rp[iF[25]]; s += rp[iF[26]]; s += rp[iF[27]];
                        }
                    }
                }
            }
        }
    }
    return s;
}

// chunked gather-OR over uint2 planes (b64 reads).
__device__ __forceinline__ void r19_gor(const uint2* __restrict__ rp,
                                        const int (&iF)[MAXD], int dm, uint2& r) {
    {
        const uint2 v0 = rp[iF[0]], v1 = rp[iF[1]], v2 = rp[iF[2]], v3 = rp[iF[3]];
        r.x |= v0.x | v1.x | v2.x | v3.x;
        r.y |= v0.y | v1.y | v2.y | v3.y;
    }
    if (dm > 4) {
        const uint2 v0 = rp[iF[4]], v1 = rp[iF[5]], v2 = rp[iF[6]], v3 = rp[iF[7]];
        r.x |= v0.x | v1.x | v2.x | v3.x;
        r.y |= v0.y | v1.y | v2.y | v3.y;
        if (dm > 8) {
            const uint2 w0 = rp[iF[8]], w1 = rp[iF[9]], w2 = rp[iF[10]], w3 = rp[iF[11]];
            r.x |= w0.x | w1.x | w2.x | w3.x;
            r.y |= w0.y | w1.y | w2.y | w3.y;
            if (dm > 12) {
                const uint2 u0 = rp[iF[12]], u1 = rp[iF[13]], u2 = rp[iF[14]], u3 = rp[iF[15]];
                r.x |= u0.x | u1.x | u2.x | u3.x;
                r.y |= u0.y | u1.y | u2.y | u3.y;
                if (dm > 16) {
                    const uint2 a0 = rp[iF[16]], a1 = rp[iF[17]], a2 = rp[iF[18]], a3 = rp[iF[19]];
                    r.x |= a0.x | a1.x | a2.x | a3.x;
                    r.y |= a0.y | a1.y | a2.y | a3.y;
                    if (dm > 20) {
                        const uint2 b0 = rp[iF[20]], b1 = rp[iF[21]], b2 = rp[iF[22]], b3 = rp[iF[23]];
                        r.x |= b0.x | b1.x | b2.x | b3.x;
                        r.y |= b0.y | b1.y | b2.y | b3.y;
                        if (dm > 24) {
                            const uint2 c0 = rp[iF[24]], c1 = rp[iF[25]], c2 = rp[iF[26]], c3 = rp[iF[27]];
                            r.x |= c0.x | c1.x | c2.x | c3.x;
                            r.y |= c0.y | c1.y | c2.y | c3.y;
                        }
                    }
                }
            }
        }
    }
}

// ---------------------------------------------------------------------------
// K1: edge scatter -> global bitsets (one edge per thread, 192 blocks).
__global__ __launch_bounds__(256) void r17_scatter(
    const int* __restrict__ ei,
    uint32_t* __restrict__ fwdb, uint32_t* __restrict__ trsb)
{
    const int e = blockIdx.x * 256 + threadIdx.x;
    if (e < EEe) {
        const int src = ei[e], dst = ei[EEe + e];
        atomicOr(&fwdb[(size_t)dst * 16 + ((src & 511) >> 5)], 1u << (src & 31));
        atomicOr(&trsb[(size_t)src * 16 + ((dst & 511) >> 5)], 1u << (dst & 31));
    }
}

// ---------------------------------------------------------------------------
// K2: extract + deg. grid 48 x 512.
// blocks 0..31: bitset -> CSR planes (identical work/order as r17_extract).
// blocks 32..47: per-graph degree chain -> d0g (identical FP op order).
__global__ __launch_bounds__(512) void r23_extract(
    const uint32_t* __restrict__ fwdb, const uint32_t* __restrict__ trsb,
    const float* __restrict__ panw,
    unsigned short* __restrict__ csrF, unsigned short* __restrict__ csrT,
    float* __restrict__ d0g)
{
    __shared__ __align__(16) uint32_t S[7168 + 1047];  // Ctmp 28KB | pa/pb/wsh
    const int blk = blockIdx.x, tid = threadIdx.x;

    if (blk < 32) {
        const int t = blk * 512 + tid;                 // 0..16383
        const int node = t & 8191;
        const uint32_t* bs = (t < 8192) ? (fwdb + (size_t)node * 16)
                                        : (trsb + (size_t)node * 16);
        unsigned short* cs = (t < 8192) ? csrF : csrT;
        int cnt = 0;
        for (int w = 0; w < 16; ++w) {
            uint32_t bits = bs[w];
            while (bits) {
                const int u = (w << 5) + __ffs(bits) - 1;
                bits &= bits - 1;
                if (cnt < MAXD) cs[(size_t)cnt * 8192 + node] = (unsigned short)u;
                ++cnt;
            }
        }
        for (int j = cnt; j < MAXD; ++j) cs[(size_t)j * 8192 + node] = PADR;
    } else {
        const int b = blk - 32;
        const int node = b * 512 + tid;
        unsigned short* Ctmp = (unsigned short*)S;     // [MAXD][512]
        float* pa  = (float*)(S + 7168);               // 513
        float* pb  = pa + 513;                         // 513
        float* wsh = pb + 513;                         // 21
        // extract forward neighbors (same order as CSR) via LDS column,
        // then load to regs with compile-time j (no scratch spill).
        {
            const uint32_t* bs = fwdb + (size_t)node * 16;
            int cnt = 0;
            for (int w = 0; w < 16; ++w) {
                uint32_t bits = bs[w];
                while (bits) {
                    const int u = (w << 5) + __ffs(bits) - 1;
                    bits &= bits - 1;
                    if (cnt < MAXD) Ctmp[cnt * 512 + tid] = (unsigned short)u;
                    ++cnt;
                }
            }
            for (int j = cnt; j < MAXD; ++j) Ctmp[j * 512 + tid] = PADR;
        }
        int iF[MAXD];
#pragma unroll
        for (int j = 0; j < MAXD; ++j) iF[j] = (int)Ctmp[j * 512 + tid];
        const int dmF = r19_wmaxdeg(iF);

        if (tid < 21) wsh[tid] = panw[tid];
        pa[tid] = 1.0f;
        if (tid == 0) { pa[512] = 0.0f; pb[512] = 0.0f; }
        __syncthreads();
        float dacc = wsh[0];
        {
            float* rp = pa; float* rn = pb;
            for (int i = 1; i <= LLp; ++i) {
                const float s = r19_gsum(rp, iF, dmF);
                rn[tid] = s;
                dacc += wsh[i] * s;
                __syncthreads();
                float* tp = rp; rp = rn; rn = tp;
            }
        }
        d0g[node] = (dacc > 0.0f) ? 1.0f / sqrtf(dacc) : 0.0f;
    }
}

// ---------------------------------------------------------------------------
// K3: mid, grid (16,12) x 512. y<4: seeded chain only (d0 precomputed);
// y in 4..11: reachability plane pairs (uint2), r19 verbatim.
__global__ __launch_bounds__(512) void r23_mid(
    const float* __restrict__ x,
    const unsigned short* __restrict__ csrF,
    const unsigned short* __restrict__ csrT,
    const float* __restrict__ panw,
    const float* __restrict__ l1w, const float* __restrict__ l1b,
    const float* __restrict__ d0g,
    float* __restrict__ h_raw, float* __restrict__ colsum,
    uint32_t* __restrict__ Rb)
{
    __shared__ __align__(16) uint32_t sbuf[2052];   // 8208 B
    const int b = blockIdx.x, y = blockIdx.y, t = threadIdx.x;
    const int node = b * 512 + t;

    if (y < 4) {
        const int c = y;
        float* pa  = (float*)sbuf;             // 513
        float* pb  = (float*)(sbuf + 513);     // 513
        float* wsh = (float*)(sbuf + 1026);    // 21
        if (t < 21) wsh[t] = panw[t];

        int idx[MAXD];
        if (c == 3) {
#pragma unroll
            for (int j = 0; j < MAXD; ++j) idx[j] = (int)csrT[(size_t)j * 8192 + node];
        } else {
#pragma unroll
            for (int j = 0; j < MAXD; ++j) idx[j] = (int)csrF[(size_t)j * 8192 + node];
        }
        const int dm2 = r19_wmaxdeg(idx);
        const float d0 = d0g[node];

        float seed;
        if (c < 3) {
            float xw = 0.0f;
            const float* xr = x + (size_t)node * NFf;
            for (int f = 0; f < NFf; ++f) xw += xr[f] * l1w[f * 3 + c];
            seed = d0 * xw;
        } else {
            seed = d0;
        }
        pa[t] = seed;
        if (t == 0) { pa[512] = 0.0f; pb[512] = 0.0f; }
        __syncthreads();
        float acc = wsh[0] * seed;
        {
            float* rp = pa; float* rn = pb;
            for (int i = 1; i <= LLp; ++i) {
                const float s = r19_gsum(rp, idx, dm2);
                rn[t] = s;
                acc += wsh[i] * s;
                __syncthreads();
                float* tp = rp; rp = rn; rn = tp;
            }
        }
        if (c < 3) h_raw[(size_t)node * 3 + c] = r17_sane(d0 * acc + l1b[c]);
        else       colsum[node] = r17_sane(d0 * acc);
    } else {
        int iF[MAXD];
#pragma unroll
        for (int j = 0; j < MAXD; ++j) iF[j] = (int)csrF[(size_t)j * 8192 + node];
        const int dmF = r19_wmaxdeg(iF);
        const int q = y - 4;                   // plane pair {2q, 2q+1}
        uint2* R1 = (uint2*)sbuf;              // 513
        uint2* R2 = R1 + 513;                  // 513
        uint2 seed;
        seed.x = ((t >> 5) == 2 * q)     ? (1u << (t & 31)) : 0u;
        seed.y = ((t >> 5) == 2 * q + 1) ? (1u << (t & 31)) : 0u;
        R1[t] = seed;
        if (t == 0) {
            uint2 z; z.x = 0u; z.y = 0u;
            R1[512] = z; R2[512] = z;
        }
        __syncthreads();
        uint2* Rp = R1; uint2* Rn = R2;
        for (int i = 0; i < LLp; ++i) {
            uint2 r = Rp[t];
            r19_gor(Rp, iF, dmF, r);
            Rn[t] = r;
            __syncthreads();
            uint2* tp = Rp; Rp = Rn; Rn = tp;
        }
        *(uint2*)(&Rb[(size_t)node * 16 + 2 * q]) = Rp[t];
    }
}

// ---------------------------------------------------------------------------
// K4: pool -- grid 16 x 512 (r19_pool verbatim).
__global__ __launch_bounds__(512) void r19_pool(
    const float* __restrict__ h_raw,
    const float* __restrict__ colsum,
    const uint32_t* __restrict__ Rb,
    const float* n1w, const float* n1b, const float* n1ms,
    const float* poolp, const float* poolb,
    const float* gwl, const float* gbl,
    float* __restrict__ x1,
    float* __restrict__ xpg,      // [BB][KPAD][3]
    float4* __restrict__ xlg,     // [BB][KP2]  (pads zeroed)
    int*   __restrict__ kidxg,    // [BB][KPAD]
    uint32_t* __restrict__ RTg)   // [BB][16][KP2] (pads zeroed)
{
    __shared__ __align__(16) uint32_t pg[2208];
    float* sc   = (float*)pg;                  // 512
    float* mv   = (float*)(pg + 512);          // 8
    float* wred = (float*)(pg + 520);          // 24
    float* xpS  = (float*)(pg + 544);          // 1248 (416*3)
    int*   kidx = (int*)(pg + 1792);           // 416
    const int b = blockIdx.x, t = threadIdx.x;
    const int lane = t & 63, wv = t >> 6;
    const float inv_n = 1.0f / (float)NNt;

    float hv0[16], hv1[16], hv2[16];
    float p0 = 0.0f, p1 = 0.0f, p2 = 0.0f;
#pragma unroll
    for (int k = 0; k < 16; ++k) {
        const float* hr = h_raw + (size_t)(k * 512 + t) * 3;
        hv0[k] = hr[0]; hv1[k] = hr[1]; hv2[k] = hr[2];
        p0 += hv0[k]; p1 += hv1[k]; p2 += hv2[k];
    }
#pragma unroll
    for (int off = 32; off; off >>= 1) {
        p0 += __shfl_xor(p0, off); p1 += __shfl_xor(p1, off); p2 += __shfl_xor(p2, off);
    }
    if (lane == 0) { wred[wv * 3 + 0] = p0; wred[wv * 3 + 1] = p1; wred[wv * 3 + 2] = p2; }
    __syncthreads();
    if (t < 3) {
        float s = 0.0f;
        for (int w = 0; w < 8; ++w) s += wred[w * 3 + t];
        mv[t] = s * inv_n;
    }
    __syncthreads();
    const float mm0 = n1ms[0] * mv[0], mm1 = n1ms[1] * mv[1], mm2 = n1ms[2] * mv[2];
    float q0 = 0.0f, q1 = 0.0f, q2 = 0.0f;
#pragma unroll
    for (int k = 0; k < 16; ++k) {
        const float d0 = hv0[k] - mm0, d1 = hv1[k] - mm1, d2 = hv2[k] - mm2;
        q0 += d0 * d0; q1 += d1 * d1; q2 += d2 * d2;
    }
#pragma unroll
    for (int off = 32; off; off >>= 1) {
        q0 += __shfl_xor(q0, off); q1 += __shfl_xor(q1, off); q2 += __shfl_xor(q2, off);
    }
    if (lane == 0) { wred[wv * 3 + 0] = q0; wred[wv * 3 + 1] = q1; wred[wv * 3 + 2] = q2; }
    __syncthreads();
    if (t < 3) {
        float s = 0.0f;
        for (int w = 0; w < 8; ++w) s += wred[w * 3 + t];
        mv[3 + t] = s * inv_n;
    }
    __syncthreads();

    const float mmv[3] = { mm0, mm1, mm2 };
    float xv[3];
#pragma unroll
    for (int c = 0; c < 3; ++c) {
        const float iv = 1.0f / sqrtf(fmaxf(mv[3 + c], 0.0f) + EPSf);
        const float o  = h_raw[(size_t)(b * NPn + t) * 3 + c] - mmv[c];
        const float tt = n1w[c] * o * iv + n1b[c];
        xv[c] = fmaxf(tt, 0.0f);
        x1[(size_t)(b * NPn + t) * 3 + c] = xv[c];
    }
    float s = poolb[0] * (xv[0] * poolp[0] + xv[1] * poolp[1] + xv[2] * poolp[2])
            + poolb[1] * colsum[b * NPn + t];
    s = tanhf(s);
    if (!(s == s)) s = 0.0f;
    sc[t] = s;
    __syncthreads();

    int cnt = 0;
    for (int u = 0; u < NPn; u += 4) {
        const float4 s4 = *(const float4*)(sc + u);
        cnt += ((s4.x > s) || (s4.x == s && (u + 0) < t)) ? 1 : 0;
        cnt += ((s4.y > s) || (s4.y == s && (u + 1) < t)) ? 1 : 0;
        cnt += ((s4.z > s) || (s4.z == s && (u + 2) < t)) ? 1 : 0;
        cnt += ((s4.w > s) || (s4.w == s && (u + 3) < t)) ? 1 : 0;
    }
    if (cnt < KKk) {                       // rank-count bijection
        const float xp0 = xv[0] * s, xp1 = xv[1] * s, xp2 = xv[2] * s;
        kidx[cnt] = t;
        xpS[cnt * 3 + 0] = xp0;
        xpS[cnt * 3 + 1] = xp1;
        xpS[cnt * 3 + 2] = xp2;
        kidxg[b * KPAD + cnt] = t;
        xpg[(size_t)(b * KPAD + cnt) * 3 + 0] = xp0;
        xpg[(size_t)(b * KPAD + cnt) * 3 + 1] = xp1;
        xpg[(size_t)(b * KPAD + cnt) * 3 + 2] = xp2;
    }
    __syncthreads();

    float Wl[9];
#pragma unroll
    for (int i2 = 0; i2 < 9; ++i2) Wl[i2] = gwl[i2];
    const float Bl0 = gbl[0], Bl1 = gbl[1], Bl2 = gbl[2];
    if (t < KP2) {
        float xl0, xl1, xl2;
        uint32_t* RT = RTg + (size_t)b * 16 * KP2 + t;
        if (t < KKk) {
            const float c0 = xpS[t * 3 + 0];
            const float c1 = xpS[t * 3 + 1];
            const float c2 = xpS[t * 3 + 2];
            xl0 = c0 * Wl[0] + c1 * Wl[3] + c2 * Wl[6] + Bl0;
            xl1 = c0 * Wl[1] + c1 * Wl[4] + c2 * Wl[7] + Bl1;
            xl2 = c0 * Wl[2] + c1 * Wl[5] + c2 * Wl[8] + Bl2;
            const uint4* rr = (const uint4*)(Rb + (size_t)(b * NPn + kidx[t]) * 16);
            const uint4 r0 = rr[0], r1 = rr[1], r2 = rr[2], r3 = rr[3];
            RT[ 0 * KP2] = r0.x; RT[ 1 * KP2] = r0.y; RT[ 2 * KP2] = r0.z; RT[ 3 * KP2] = r0.w;
            RT[ 4 * KP2] = r1.x; RT[ 5 * KP2] = r1.y; RT[ 6 * KP2] = r1.z; RT[ 7 * KP2] = r1.w;
            RT[ 8 * KP2] = r2.x; RT[ 9 * KP2] = r2.y; RT[10 * KP2] = r2.z; RT[11 * KP2] = r2.w;
            RT[12 * KP2] = r3.x; RT[13 * KP2] = r3.y; RT[14 * KP2] = r3.z; RT[15 * KP2] = r3.w;
        } else {
            xl0 = 0.0f; xl1 = 0.0f; xl2 = 0.0f;
#pragma unroll
            for (int w = 0; w < 16; ++w) RT[w * KP2] = 0u;
        }
        xlg[(size_t)(b * KP2 + t)] = make_float4(xl0, xl1, xl2, 0.0f);
    }
}

// ---------------------------------------------------------------------------
// K5: GAT -- grid (16,52) x 512, one wave per output row, no LDS (r19 verbatim).
__global__ __launch_bounds__(512) void r19_gat(
    const float* __restrict__ xpg,
    const float4* __restrict__ xlg,
    const int* __restrict__ kidxg,
    const uint32_t* __restrict__ RTg,
    const float* __restrict__ gwr, const float* __restrict__ gbr,
    const float* __restrict__ gatt, const float* __restrict__ gbias,
    float* __restrict__ g_raw)
{
    const int b = blockIdx.x, y = blockIdx.y, t = threadIdx.x;
    const int lane = t & 63, wv = t >> 6;
    const int i = y * 8 + wv;                  // row of this wave
    if (i >= KKk) return;

    float Wr[9];
#pragma unroll
    for (int k = 0; k < 9; ++k) Wr[k] = gwr[k];
    const float Br0 = gbr[0], Br1 = gbr[1], Br2 = gbr[2];
    const float At0 = gatt[0], At1 = gatt[1], At2 = gatt[2];
    const float Gb0 = gbias[0], Gb1 = gbias[1], Gb2 = gbias[2];

    const int bi = kidxg[b * KPAD + i];
    const float c0 = xpg[(size_t)(b * KPAD + i) * 3 + 0];
    const float c1 = xpg[(size_t)(b * KPAD + i) * 3 + 1];
    const float c2 = xpg[(size_t)(b * KPAD + i) * 3 + 2];
    const float xr0 = c0 * Wr[0] + c1 * Wr[3] + c2 * Wr[6] + Br0;
    const float xr1 = c0 * Wr[1] + c1 * Wr[4] + c2 * Wr[7] + Br1;
    const float xr2 = c0 * Wr[2] + c1 * Wr[5] + c2 * Wr[8] + Br2;

    const uint32_t mbit = 1u << (bi & 31);
    const uint32_t* Rw = RTg + (size_t)(b * 16 + (bi >> 5)) * KP2;
    const float4* xlb = xlg + (size_t)b * KP2;

    float mx = -3e38f, lsum = 0.0f, b0 = 0.0f, b1 = 0.0f, b2 = 0.0f;
#pragma unroll
    for (int it = 0; it < 7; ++it) {
        const int j = lane + it * 64;          // < 448, coalesced
        const uint32_t rw = Rw[j];
        const float4 xlv = xlb[j];
        const float xl0 = xlv.x, xl1 = xlv.y, xl2 = xlv.z;
        const bool valid = (rw & mbit) || (j == i);   // pads auto-invalid
        float e0 = xr0 + xl0; e0 = e0 > 0.0f ? e0 : 0.2f * e0;
        float e1 = xr1 + xl1; e1 = e1 > 0.0f ? e1 : 0.2f * e1;
        float e2 = xr2 + xl2; e2 = e2 > 0.0f ? e2 : 0.2f * e2;
        const float sv = At0 * e0 + At1 * e1 + At2 * e2;
        if (valid) {
            if (sv > mx) {
                const float r = __expf(mx - sv);
                lsum *= r; b0 *= r; b1 *= r; b2 *= r;
                mx = sv;
            }
            const float pj = __expf(sv - mx);
            lsum += pj;
            b0 += pj * xl0; b1 += pj * xl1; b2 += pj * xl2;
        }
    }
#pragma unroll
    for (int off = 32; off; off >>= 1) {       // butterfly LSE merge
        const float mo = __shfl_xor(mx, off);
        const float lo = __shfl_xor(lsum, off);
        const float d0 = __shfl_xor(b0, off);
        const float d1 = __shfl_xor(b1, off);
        const float d2 = __shfl_xor(b2, off);
        const float M  = fmaxf(mx, mo);
        const float ea = __expf(mx - M), eb = __expf(mo - M);
        lsum = lsum * ea + lo * eb;
        b0 = b0 * ea + d0 * eb;
        b1 = b1 * ea + d1 * eb;
        b2 = b2 * ea + d2 * eb;
        mx = M;
    }
    if (lane == 0) {
        const float rl = 1.0f / fmaxf(lsum, 1e-30f);
        g_raw[(size_t)(b * KPAD + i) * 3 + 0] = r17_sane(b0 * rl + Gb0);
        g_raw[(size_t)(b * KPAD + i) * 3 + 1] = r17_sane(b1 * rl + Gb1);
        g_raw[(size_t)(b * KPAD + i) * 3 + 2] = r17_sane(b2 * rl + Gb2);
    }
}

// ---------------------------------------------------------------------------
// K6: head (r17_head verbatim).
__global__ __launch_bounds__(512) void r17_head(
    const float* __restrict__ g_raw,
    const float* __restrict__ x1,
    const float* __restrict__ x,
    const int* __restrict__ cnid,
    const int* __restrict__ amask,
    const float* n2w, const float* n2b, const float* n2ms,
    const float* v1w, const float* v1b,
    const float* v2w, const float* v2b,
    const float* v3w, const float* v3b,
    const float* a1w, const float* a1b,
    const float* a2w, const float* a2b,
    const float* a3w, const float* a3b,
    float* __restrict__ out)
{
    __shared__ float wred[24];
    __shared__ float mv[6];
    __shared__ float gp[3];
    __shared__ float feat[19];
    __shared__ float h1a[10], h1v[10], h2a[5], h2v[5];
    __shared__ float a3[50];
    __shared__ float vout_s, amean_s;
    const int b = blockIdx.x, t = threadIdx.x;
    const int lane = t & 63, wv = t >> 6;
    const float denom = 1.0f / (float)(BB * KKk);

    float gv0[13], gv1[13], gv2[13];
    float p0 = 0.0f, p1 = 0.0f, p2 = 0.0f;
#pragma unroll
    for (int k = 0; k < 13; ++k) {
        const int r = k * 512 + t;
        float q0 = 0.0f, q1 = 0.0f, q2 = 0.0f;
        if (r < BB * KKk) {
            const int bq = r / KKk, iq = r - bq * KKk;
            const float* gr = g_raw + (size_t)(bq * KPAD + iq) * 3;
            q0 = gr[0]; q1 = gr[1]; q2 = gr[2];
        }
        gv0[k] = q0; gv1[k] = q1; gv2[k] = q2;
        p0 += q0; p1 += q1; p2 += q2;
    }
#pragma unroll
    for (int off = 32; off; off >>= 1) {
        p0 += __shfl_xor(p0, off); p1 += __shfl_xor(p1, off); p2 += __shfl_xor(p2, off);
    }
    if (lane == 0) { wred[wv * 3 + 0] = p0; wred[wv * 3 + 1] = p1; wred[wv * 3 + 2] = p2; }
    __syncthreads();
    if (t < 3) {
        float s = 0.0f;
        for (int w = 0; w < 8; ++w) s += wred[w * 3 + t];
        mv[t] = s * denom;
    }
    __syncthreads();
    const float mm0 = n2ms[0] * mv[0], mm1 = n2ms[1] * mv[1], mm2 = n2ms[2] * mv[2];
    float q0a = 0.0f, q1a = 0.0f, q2a = 0.0f;
#pragma unroll
    for (int k = 0; k < 13; ++k) {
        const int r = k * 512 + t;
        if (r < BB * KKk) {
            const float d0 = gv0[k] - mm0, d1 = gv1[k] - mm1, d2 = gv2[k] - mm2;
            q0a += d0 * d0; q1a += d1 * d1; q2a += d2 * d2;
        }
    }
#pragma unroll
    for (int off = 32; off; off >>= 1) {
        q0a += __shfl_xor(q0a, off); q1a += __shfl_xor(q1a, off); q2a += __shfl_xor(q2a, off);
    }
    if (lane == 0) { wred[wv * 3 + 0] = q0a; wred[wv * 3 + 1] = q1a; wred[wv * 3 + 2] = q2a; }
    __syncthreads();
    if (t < 3) {
        float s = 0.0f;
        for (int w = 0; w < 8; ++w) s += wred[w * 3 + t];
        mv[3 + t] = s * denom;
    }
    __syncthreads();

    const float mmv[3] = { mm0, mm1, mm2 };
    float s3[3] = { 0.0f, 0.0f, 0.0f };
    if (t < KKk) {
        const size_t r = (size_t)(b * KPAD + t) * 3;
#pragma unroll
        for (int c = 0; c < 3; ++c) {
            const float iv = 1.0f / sqrtf(fmaxf(mv[3 + c], 0.0f) + EPSf);
            s3[c] = fmaxf((g_raw[r + c] - mmv[c]) * iv * n2w[c] + n2b[c], 0.0f);
        }
    }
    float g0 = s3[0], g1 = s3[1], g2 = s3[2];
#pragma unroll
    for (int off = 32; off; off >>= 1) {
        g0 += __shfl_xor(g0, off); g1 += __shfl_xor(g1, off); g2 += __shfl_xor(g2, off);
    }
    if (lane == 0) { wred[wv * 3 + 0] = g0; wred[wv * 3 + 1] = g1; wred[wv * 3 + 2] = g2; }
    __syncthreads();
    if (t < 3) {
        float s = 0.0f;
        for (int w = 0; w < 8; ++w) s += wred[w * 3 + t];
        gp[t] = s;
    }
    __syncthreads();

    if (t < 19) {
        const int gidx = cnid[b] + b * KKk;        // faithful: pooled-K offsets
        float fv;
        if (t < 13)      fv = x[(size_t)gidx * NFf + t];
        else if (t < 16) fv = x1[(size_t)gidx * 3 + (t - 13)];
        else             fv = gp[t - 16];
        feat[t] = fv;
    }
    __syncthreads();

    if (t < 10) {
        float s = a1b[t];
        for (int f = 0; f < 19; ++f) s += feat[f] * a1w[f * 10 + t];
        h1a[t] = fmaxf(s, 0.0f);
    } else if (t >= 64 && t < 74) {
        const int j = t - 64;
        float s = v1b[j];
        for (int f = 0; f < 19; ++f) s += feat[f] * v1w[f * 10 + j];
        h1v[j] = fmaxf(s, 0.0f);
    }
    __syncthreads();
    if (t < 5) {
        float s = a2b[t];
        for (int k = 0; k < 10; ++k) s += h1a[k] * a2w[k * 5 + t];
        h2a[t] = fmaxf(s, 0.0f);
    } else if (t >= 64 && t < 69) {
        const int j = t - 64;
        float s = v2b[j];
        for (int k = 0; k < 10; ++k) s += h1v[k] * v2w[k * 5 + j];
        h2v[j] = fmaxf(s, 0.0f);
    }
    __syncthreads();
    if (t < 50) {
        float s = a3b[t];
        for (int k = 0; k < 5; ++k) s += h2a[k] * a3w[k * 50 + t];
        a3[t] = s;
    } else if (t == 64) {
        float s = v3b[0];
        for (int k = 0; k < 5; ++k) s += h2v[k] * v3w[k];
        vout_s = s;
    }
    __syncthreads();
    if (t == 0) {
        float s = 0.0f;
        for (int k = 0; k < 50; ++k) s += a3[k];
        amean_s = s * (1.0f / 50.0f);
    }
    __syncthreads();
    if (t < 50) {
        float q = vout_s + a3[t] - amean_s;
        if (!(q == q)) q = 0.0f;
        q = fminf(fmaxf(q, -QCLMP), QCLMP);
        out[b * NAa + t] = (amask[b * NAa + t] == 0) ? -1e8f : q;   // FP32
    }
}

// ---------------------------------------------------------------------------
extern "C" void kernel_launch(void* const* d_in, const int* in_sizes, int n_in,
                              void* d_out, int out_size, void* d_ws, size_t ws_size,
                              hipStream_t stream) {
    (void)in_sizes; (void)n_in; (void)out_size;
    const float* x     = (const float*)d_in[0];
    const int* ei      = (const int*)d_in[1];
    const int* cnid    = (const int*)d_in[4];
    const int* amask   = (const int*)d_in[5];
    const float* panw  = (const float*)d_in[6];
    const float* l1w   = (const float*)d_in[7];
    const float* l1b   = (const float*)d_in[8];
    const float* n1w   = (const float*)d_in[9];
    const float* n1b   = (const float*)d_in[10];
    const float* n1ms  = (const float*)d_in[11];
    const float* poolp = (const float*)d_in[12];
    const float* poolb = (const float*)d_in[13];
    const float* gwl   = (const float*)d_in[14];
    const float* gbl   = (const float*)d_in[15];
    const float* gwr   = (const float*)d_in[16];
    const float* gbr   = (const float*)d_in[17];
    const float* gatt  = (const float*)d_in[18];
    const float* gbias = (const float*)d_in[19];
    const float* n2w   = (const float*)d_in[20];
    const float* n2b   = (const float*)d_in[21];
    const float* n2ms  = (const float*)d_in[22];
    const float* v1w   = (const float*)d_in[23];
    const float* v1b   = (const float*)d_in[24];
    const float* v2w   = (const float*)d_in[25];
    const float* v2b   = (const float*)d_in[26];
    const float* v3w   = (const float*)d_in[27];
    const float* v3b   = (const float*)d_in[28];
    const float* a1w   = (const float*)d_in[29];
    const float* a1b   = (const float*)d_in[30];
    const float* a2w   = (const float*)d_in[31];
    const float* a2b   = (const float*)d_in[32];
    const float* a3w   = (const float*)d_in[33];
    const float* a3b   = (const float*)d_in[34];
    float* out         = (float*)d_out;

    // ws layout (bytes): fwdb 512K | trsb 512K | Rb 512K | csrF | csrT | d0g |
    //                    h_raw | x1 | colsum | g_raw | xpg | xlg(f4) | kidxg | RTg
    uint8_t* wsb = (uint8_t*)d_ws;
    uint32_t* fwdb = (uint32_t*)wsb;
    uint32_t* trsb = (uint32_t*)(wsb + 524288);
    uint32_t* Rb   = (uint32_t*)(wsb + 1048576);
    unsigned short* csrF = (unsigned short*)(wsb + 1572864);
    unsigned short* csrT = csrF + (size_t)MAXD * 8192;
    float* d0g    = (float*)(csrT + (size_t)MAXD * 8192);
    float* h_raw  = d0g + NNt;
    float* x1     = h_raw + (size_t)NNt * 3;
    float* colsum = x1 + (size_t)NNt * 3;
    float* g_raw  = colsum + NNt;
    float* xpg    = g_raw + (size_t)BB * KPAD * 3;
    float4* xlg   = (float4*)(xpg + (size_t)BB * KPAD * 3);
    int*   kidxg  = (int*)(xlg + (size_t)BB * KP2);
    uint32_t* RTg = (uint32_t*)(kidxg + (size_t)BB * KPAD);
    const size_t needed = (size_t)((uint8_t*)(RTg + (size_t)BB * 16 * KP2) - wsb);
    if (ws_size < needed) return;

    hipMemsetAsync(fwdb, 0, 1048576, stream);            // both bitsets
    r17_scatter<<<dim3((EEe + 255) / 256), dim3(256), 0, stream>>>(ei, fwdb, trsb);
    r23_extract<<<dim3(48), dim3(512), 0, stream>>>(fwdb, trsb, panw,
                                                    csrF, csrT, d0g);
    r23_mid<<<dim3(16, 12), dim3(512), 0, stream>>>(x, csrF, csrT, panw, l1w, l1b,
                                                    d0g, h_raw, colsum, Rb);
    r19_pool<<<dim3(16), dim3(512), 0, stream>>>(h_raw, colsum, Rb,
                                                 n1w, n1b, n1ms, poolp, poolb,
                                                 gwl, gbl,
                                                 x1, xpg, xlg, kidxg, RTg);
    r19_gat<<<dim3(16, 52), dim3(512), 0, stream>>>(xpg, xlg, kidxg, RTg,
                                                    gwr, gbr, gatt, gbias, g_raw);
    r17_head<<<dim3(16), dim3(512), 0, stream>>>(g_raw, x1, x, cnid, amask,
                                                 n2w, n2b, n2ms, v1w, v1b, v2w, v2b, v3w, v3b,
                                                 a1w, a1b, a2w, a2b, a3w, a3b, out);
}

// Round 7
// 201.537 us; speedup vs baseline: 1.7377x; 1.0039x over previous
//
#include <hip/hip_runtime.h>
#include <stdint.h>
#include <math.h>

// PANConcDQL round 24 -- math identical to r23 (passed, absmax 0.0).
// Model: harness floor ~120us (2x256MiB poison fills + tiny resets), our
// kernels ~80us. Serial skeleton: adjacency -> deg(20r) -> seeded(20r) is
// algorithmic. This round: reachability (needs only adjacency) moves INTO
// the extract dispatch, concurrent with the deg chain, with bit-exact
// early-exit (bitsets saturate; unchanged round == all future rounds
// identical). mid becomes seeded-only (16,4) -- its b64 reach pole is gone.
#define BB   16
#define NPn  512
#define LLp  20
#define NAa  50
#define KKk  410
#define NNt  (BB * NPn)   // 8192
#define EEe  (6 * NNt)    // 49152
#define NFf  13
#define KPAD 416
#define KP2  448          // padded GAT staging width (7*64)
#define EPSf 1e-5f
#define QCLMP 1e6f
#define MAXD 28
#define PADR 512

__device__ __forceinline__ float r17_sane(float v) {
    if (!(v == v)) return 0.0f;
    return fminf(fmaxf(v, -1e15f), 1e15f);
}

// wave-max of per-thread real degree (pads are PADR).
__device__ __forceinline__ int r19_wmaxdeg(const int (&iF)[MAXD]) {
    int deg = 0;
#pragma unroll
    for (int j = 0; j < MAXD; ++j) deg += (iF[j] != PADR) ? 1 : 0;
#pragma unroll
    for (int off = 32; off; off >>= 1) {
        const int o = __shfl_xor(deg, off);
        deg = o > deg ? o : deg;
    }
    return deg;
}

// chunked gather-sum: compile-time indices only; dm is wave-uniform.
__device__ __forceinline__ float r19_gsum(const float* __restrict__ rp,
                                          const int (&iF)[MAXD], int dm) {
    float s = 0.0f;
    s += rp[iF[0]]; s += rp[iF[1]]; s += rp[iF[2]]; s += rp[iF[3]];
    if (dm > 4) {
        s += rp[iF[4]]; s += rp[iF[5]]; s += rp[iF[6]]; s += rp[iF[7]];
        if (dm > 8) {
            s += rp[iF[8]]; s += rp[iF[9]]; s += rp[iF[10]]; s += rp[iF[11]];
            if (dm > 12) {
                s += rp[iF[12]]; s += rp[iF[13]]; s += rp[iF[14]]; s += rp[iF[15]];
                if (dm > 16) {
                    s += rp[iF[16]]; s += rp[iF[17]]; s += rp[iF[18]]; s += rp[iF[19]];
                    if (dm > 20) {
                        s += rp[iF[20]]; s += rp[iF[21]]; s += rp[iF[22]]; s += rp[iF[23]];
                        if (dm > 24) {
                            s += rp[iF[24]]; s += rp[iF[25]]; s += rp[iF[26]]; s += rp[iF[27]];
                        }
                    }
                }
            }
        }
    }
    return s;
}

// chunked gather-OR over uint2 planes (b64 reads).
__device__ __forceinline__ void r19_gor(const uint2* __restrict__ rp,
                                        const int (&iF)[MAXD], int dm, uint2& r) {
    {
        const uint2 v0 = rp[iF[0]], v1 = rp[iF[1]], v2 = rp[iF[2]], v3 = rp[iF[3]];
        r.x |= v0.x | v1.x | v2.x | v3.x;
        r.y |= v0.y | v1.y | v2.y | v3.y;
    }
    if (dm > 4) {
        const uint2 v0 = rp[iF[4]], v1 = rp[iF[5]], v2 = rp[iF[6]], v3 = rp[iF[7]];
        r.x |= v0.x | v1.x | v2.x | v3.x;
        r.y |= v0.y | v1.y | v2.y | v3.y;
        if (dm > 8) {
            const uint2 w0 = rp[iF[8]], w1 = rp[iF[9]], w2 = rp[iF[10]], w3 = rp[iF[11]];
            r.x |= w0.x | w1.x | w2.x | w3.x;
            r.y |= w0.y | w1.y | w2.y | w3.y;
            if (dm > 12) {
                const uint2 u0 = rp[iF[12]], u1 = rp[iF[13]], u2 = rp[iF[14]], u3 = rp[iF[15]];
                r.x |= u0.x | u1.x | u2.x | u3.x;
                r.y |= u0.y | u1.y | u2.y | u3.y;
                if (dm > 16) {
                    const uint2 a0 = rp[iF[16]], a1 = rp[iF[17]], a2 = rp[iF[18]], a3 = rp[iF[19]];
                    r.x |= a0.x | a1.x | a2.x | a3.x;
                    r.y |= a0.y | a1.y | a2.y | a3.y;
                    if (dm > 20) {
                        const uint2 b0 = rp[iF[20]], b1 = rp[iF[21]], b2 = rp[iF[22]], b3 = rp[iF[23]];
                        r.x |= b0.x | b1.x | b2.x | b3.x;
                        r.y |= b0.y | b1.y | b2.y | b3.y;
                        if (dm > 24) {
                            const uint2 c0 = rp[iF[24]], c1 = rp[iF[25]], c2 = rp[iF[26]], c3 = rp[iF[27]];
                            r.x |= c0.x | c1.x | c2.x | c3.x;
                            r.y |= c0.y | c1.y | c2.y | c3.y;
                        }
                    }
                }
            }
        }
    }
}

// extract forward-neighbor list for `node` from bitset into LDS column, then
// caller loads to regs with compile-time j (identical order to CSR extract).
__device__ __forceinline__ void r24_bsextract(
    const uint32_t* __restrict__ bs, unsigned short* __restrict__ Ctmp, int tid)
{
    int cnt = 0;
    for (int w = 0; w < 16; ++w) {
        uint32_t bits = bs[w];
        while (bits) {
            const int u = (w << 5) + __ffs(bits) - 1;
            bits &= bits - 1;
            if (cnt < MAXD) Ctmp[cnt * 512 + tid] = (unsigned short)u;
            ++cnt;
        }
    }
    for (int j = cnt; j < MAXD; ++j) Ctmp[j * 512 + tid] = PADR;
}

// ---------------------------------------------------------------------------
// K1: edge scatter -> global bitsets (one edge per thread, 192 blocks).
__global__ __launch_bounds__(256) void r17_scatter(
    const int* __restrict__ ei,
    uint32_t* __restrict__ fwdb, uint32_t* __restrict__ trsb)
{
    const int e = blockIdx.x * 256 + threadIdx.x;
    if (e < EEe) {
        const int src = ei[e], dst = ei[EEe + e];
        atomicOr(&fwdb[(size_t)dst * 16 + ((src & 511) >> 5)], 1u << (src & 31));
        atomicOr(&trsb[(size_t)src * 16 + ((dst & 511) >> 5)], 1u << (dst & 31));
    }
}

// ---------------------------------------------------------------------------
// K2: extract + deg + reach. grid 176 x 512.
// blocks 0..31:  bitset -> CSR planes (verbatim r17_extract work/order).
// blocks 32..47: per-graph degree chain -> d0g (verbatim r23).
// blocks 48..175: reachability plane pairs with bit-exact early-exit.
__global__ __launch_bounds__(512) void r24_extract(
    const uint32_t* __restrict__ fwdb, const uint32_t* __restrict__ trsb,
    const float* __restrict__ panw,
    unsigned short* __restrict__ csrF, unsigned short* __restrict__ csrT,
    float* __restrict__ d0g, uint32_t* __restrict__ Rb)
{
    __shared__ __align__(16) uint32_t S[9240];   // Ctmp 7168 | chain/reach buf
    const int blk = blockIdx.x, tid = threadIdx.x;

    if (blk < 32) {
        const int t = blk * 512 + tid;                 // 0..16383
        const int node = t & 8191;
        const uint32_t* bs = (t < 8192) ? (fwdb + (size_t)node * 16)
                                        : (trsb + (size_t)node * 16);
        unsigned short* cs = (t < 8192) ? csrF : csrT;
        int cnt = 0;
        for (int w = 0; w < 16; ++w) {
            uint32_t bits = bs[w];
            while (bits) {
                const int u = (w << 5) + __ffs(bits) - 1;
                bits &= bits - 1;
                if (cnt < MAXD) cs[(size_t)cnt * 8192 + node] = (unsigned short)u;
                ++cnt;
            }
        }
        for (int j = cnt; j < MAXD; ++j) cs[(size_t)j * 8192 + node] = PADR;
    } else if (blk < 48) {
        // ---- degree chain (20 rounds, b32) ----
        const int b = blk - 32;
        const int node = b * 512 + tid;
        unsigned short* Ctmp = (unsigned short*)S;     // [MAXD][512]
        float* pa  = (float*)(S + 7168);               // 513
        float* pb  = pa + 513;                         // 513
        float* wsh = pb + 513;                         // 21
        r24_bsextract(fwdb + (size_t)node * 16, Ctmp, tid);
        int iF[MAXD];
#pragma unroll
        for (int j = 0; j < MAXD; ++j) iF[j] = (int)Ctmp[j * 512 + tid];
        const int dmF = r19_wmaxdeg(iF);

        if (tid < 21) wsh[tid] = panw[tid];
        pa[tid] = 1.0f;
        if (tid == 0) { pa[512] = 0.0f; pb[512] = 0.0f; }
        __syncthreads();
        float dacc = wsh[0];
        {
            float* rp = pa; float* rn = pb;
            for (int i = 1; i <= LLp; ++i) {
                const float s = r19_gsum(rp, iF, dmF);
                rn[tid] = s;
                dacc += wsh[i] * s;
                __syncthreads();
                float* tp = rp; rp = rn; rn = tp;
            }
        }
        d0g[node] = (dacc > 0.0f) ? 1.0f / sqrtf(dacc) : 0.0f;
    } else {
        // ---- reachability pair {2q,2q+1} with early-exit (bit-exact) ----
        const int rix = blk - 48;                      // 0..127
        const int b = rix >> 3, q = rix & 7;
        const int node = b * 512 + tid;
        unsigned short* Ctmp = (unsigned short*)S;     // [MAXD][512]
        uint2* R1 = (uint2*)(S + 7168);                // 513
        uint2* R2 = R1 + 513;                          // 513
        uint32_t* flags = (uint32_t*)(R2 + 513);       // 20
        r24_bsextract(fwdb + (size_t)node * 16, Ctmp, tid);
        int iF[MAXD];
#pragma unroll
        for (int j = 0; j < MAXD; ++j) iF[j] = (int)Ctmp[j * 512 + tid];
        const int dmF = r19_wmaxdeg(iF);

        uint2 seed;
        seed.x = ((tid >> 5) == 2 * q)     ? (1u << (tid & 31)) : 0u;
        seed.y = ((tid >> 5) == 2 * q + 1) ? (1u << (tid & 31)) : 0u;
        R1[tid] = seed;
        if (tid == 0) {
            uint2 z; z.x = 0u; z.y = 0u;
            R1[512] = z; R2[512] = z;
        }
        if (tid < LLp) flags[tid] = 0u;
        __syncthreads();
        uint2* Rp = R1; uint2* Rn = R2;
        for (int i = 0; i < LLp; ++i) {
            uint2 r = Rp[tid];
            const uint2 old = r;
            r19_gor(Rp, iF, dmF, r);
            Rn[tid] = r;
            if ((r.x != old.x) | (r.y != old.y)) flags[i] = 1u;
            __syncthreads();
            uint2* tp = Rp; Rp = Rn; Rn = tp;
            if (flags[i] == 0u) break;   // saturated: all later rounds identical
        }
        *(uint2*)(&Rb[(size_t)node * 16 + 2 * q]) = Rp[tid];
    }
}

// ---------------------------------------------------------------------------
// K3: mid, grid (16,4) x 512. Seeded chains only (d0 precomputed).
__global__ __launch_bounds__(512) void r24_mid(
    const float* __restrict__ x,
    const unsigned short* __restrict__ csrF,
    const unsigned short* __restrict__ csrT,
    const float* __restrict__ panw,
    const float* __restrict__ l1w, const float* __restrict__ l1b,
    const float* __restrict__ d0g,
    float* __restrict__ h_raw, float* __restrict__ colsum)
{
    __shared__ __align__(16) uint32_t sbuf[1047];
    const int b = blockIdx.x, c = blockIdx.y, t = threadIdx.x;
    const int node = b * 512 + t;

    float* pa  = (float*)sbuf;             // 513
    float* pb  = (float*)(sbuf + 513);     // 513
    float* wsh = (float*)(sbuf + 1026);    // 21
    if (t < 21) wsh[t] = panw[t];

    int idx[MAXD];
    if (c == 3) {
#pragma unroll
        for (int j = 0; j < MAXD; ++j) idx[j] = (int)csrT[(size_t)j * 8192 + node];
    } else {
#pragma unroll
        for (int j = 0; j < MAXD; ++j) idx[j] = (int)csrF[(size_t)j * 8192 + node];
    }
    const int dm2 = r19_wmaxdeg(idx);
    const float d0 = d0g[node];

    float seed;
    if (c < 3) {
        float xw = 0.0f;
        const float* xr = x + (size_t)node * NFf;
        for (int f = 0; f < NFf; ++f) xw += xr[f] * l1w[f * 3 + c];
        seed = d0 * xw;
    } else {
        seed = d0;
    }
    pa[t] = seed;
    if (t == 0) { pa[512] = 0.0f; pb[512] = 0.0f; }
    __syncthreads();
    float acc = wsh[0] * seed;
    {
        float* rp = pa; float* rn = pb;
        for (int i = 1; i <= LLp; ++i) {
            const float s = r19_gsum(rp, idx, dm2);
            rn[t] = s;
            acc += wsh[i] * s;
            __syncthreads();
            float* tp = rp; rp = rn; rn = tp;
        }
    }
    if (c < 3) h_raw[(size_t)node * 3 + c] = r17_sane(d0 * acc + l1b[c]);
    else       colsum[node] = r17_sane(d0 * acc);
}

// ---------------------------------------------------------------------------
// K4: pool -- grid 16 x 512 (r19_pool verbatim).
__global__ __launch_bounds__(512) void r19_pool(
    const float* __restrict__ h_raw,
    const float* __restrict__ colsum,
    const uint32_t* __restrict__ Rb,
    const float* n1w, const float* n1b, const float* n1ms,
    const float* poolp, const float* poolb,
    const float* gwl, const float* gbl,
    float* __restrict__ x1,
    float* __restrict__ xpg,      // [BB][KPAD][3]
    float4* __restrict__ xlg,     // [BB][KP2]  (pads zeroed)
    int*   __restrict__ kidxg,    // [BB][KPAD]
    uint32_t* __restrict__ RTg)   // [BB][16][KP2] (pads zeroed)
{
    __shared__ __align__(16) uint32_t pg[2208];
    float* sc   = (float*)pg;                  // 512
    float* mv   = (float*)(pg + 512);          // 8
    float* wred = (float*)(pg + 520);          // 24
    float* xpS  = (float*)(pg + 544);          // 1248 (416*3)
    int*   kidx = (int*)(pg + 1792);           // 416
    const int b = blockIdx.x, t = threadIdx.x;
    const int lane = t & 63, wv = t >> 6;
    const float inv_n = 1.0f / (float)NNt;

    float hv0[16], hv1[16], hv2[16];
    float p0 = 0.0f, p1 = 0.0f, p2 = 0.0f;
#pragma unroll
    for (int k = 0; k < 16; ++k) {
        const float* hr = h_raw + (size_t)(k * 512 + t) * 3;
        hv0[k] = hr[0]; hv1[k] = hr[1]; hv2[k] = hr[2];
        p0 += hv0[k]; p1 += hv1[k]; p2 += hv2[k];
    }
#pragma unroll
    for (int off = 32; off; off >>= 1) {
        p0 += __shfl_xor(p0, off); p1 += __shfl_xor(p1, off); p2 += __shfl_xor(p2, off);
    }
    if (lane == 0) { wred[wv * 3 + 0] = p0; wred[wv * 3 + 1] = p1; wred[wv * 3 + 2] = p2; }
    __syncthreads();
    if (t < 3) {
        float s = 0.0f;
        for (int w = 0; w < 8; ++w) s += wred[w * 3 + t];
        mv[t] = s * inv_n;
    }
    __syncthreads();
    const float mm0 = n1ms[0] * mv[0], mm1 = n1ms[1] * mv[1], mm2 = n1ms[2] * mv[2];
    float q0 = 0.0f, q1 = 0.0f, q2 = 0.0f;
#pragma unroll
    for (int k = 0; k < 16; ++k) {
        const float d0 = hv0[k] - mm0, d1 = hv1[k] - mm1, d2 = hv2[k] - mm2;
        q0 += d0 * d0; q1 += d1 * d1; q2 += d2 * d2;
    }
#pragma unroll
    for (int off = 32; off; off >>= 1) {
        q0 += __shfl_xor(q0, off); q1 += __shfl_xor(q1, off); q2 += __shfl_xor(q2, off);
    }
    if (lane == 0) { wred[wv * 3 + 0] = q0; wred[wv * 3 + 1] = q1; wred[wv * 3 + 2] = q2; }
    __syncthreads();
    if (t < 3) {
        float s = 0.0f;
        for (int w = 0; w < 8; ++w) s += wred[w * 3 + t];
        mv[3 + t] = s * inv_n;
    }
    __syncthreads();

    const float mmv[3] = { mm0, mm1, mm2 };
    float xv[3];
#pragma unroll
    for (int c = 0; c < 3; ++c) {
        const float iv = 1.0f / sqrtf(fmaxf(mv[3 + c], 0.0f) + EPSf);
        const float o  = h_raw[(size_t)(b * NPn + t) * 3 + c] - mmv[c];
        const float tt = n1w[c] * o * iv + n1b[c];
        xv[c] = fmaxf(tt, 0.0f);
        x1[(size_t)(b * NPn + t) * 3 + c] = xv[c];
    }
    float s = poolb[0] * (xv[0] * poolp[0] + xv[1] * poolp[1] + xv[2] * poolp[2])
            + poolb[1] * colsum[b * NPn + t];
    s = tanhf(s);
    if (!(s == s)) s = 0.0f;
    sc[t] = s;
    __syncthreads();

    int cnt = 0;
    for (int u = 0; u < NPn; u += 4) {
        const float4 s4 = *(const float4*)(sc + u);
        cnt += ((s4.x > s) || (s4.x == s && (u + 0) < t)) ? 1 : 0;
        cnt += ((s4.y > s) || (s4.y == s && (u + 1) < t)) ? 1 : 0;
        cnt += ((s4.z > s) || (s4.z == s && (u + 2) < t)) ? 1 : 0;
        cnt += ((s4.w > s) || (s4.w == s && (u + 3) < t)) ? 1 : 0;
    }
    if (cnt < KKk) {                       // rank-count bijection
        const float xp0 = xv[0] * s, xp1 = xv[1] * s, xp2 = xv[2] * s;
        kidx[cnt] = t;
        xpS[cnt * 3 + 0] = xp0;
        xpS[cnt * 3 + 1] = xp1;
        xpS[cnt * 3 + 2] = xp2;
        kidxg[b * KPAD + cnt] = t;
        xpg[(size_t)(b * KPAD + cnt) * 3 + 0] = xp0;
        xpg[(size_t)(b * KPAD + cnt) * 3 + 1] = xp1;
        xpg[(size_t)(b * KPAD + cnt) * 3 + 2] = xp2;
    }
    __syncthreads();

    float Wl[9];
#pragma unroll
    for (int i2 = 0; i2 < 9; ++i2) Wl[i2] = gwl[i2];
    const float Bl0 = gbl[0], Bl1 = gbl[1], Bl2 = gbl[2];
    if (t < KP2) {
        float xl0, xl1, xl2;
        uint32_t* RT = RTg + (size_t)b * 16 * KP2 + t;
        if (t < KKk) {
            const float c0 = xpS[t * 3 + 0];
            const float c1 = xpS[t * 3 + 1];
            const float c2 = xpS[t * 3 + 2];
            xl0 = c0 * Wl[0] + c1 * Wl[3] + c2 * Wl[6] + Bl0;
            xl1 = c0 * Wl[1] + c1 * Wl[4] + c2 * Wl[7] + Bl1;
            xl2 = c0 * Wl[2] + c1 * Wl[5] + c2 * Wl[8] + Bl2;
            const uint4* rr = (const uint4*)(Rb + (size_t)(b * NPn + kidx[t]) * 16);
            const uint4 r0 = rr[0], r1 = rr[1], r2 = rr[2], r3 = rr[3];
            RT[ 0 * KP2] = r0.x; RT[ 1 * KP2] = r0.y; RT[ 2 * KP2] = r0.z; RT[ 3 * KP2] = r0.w;
            RT[ 4 * KP2] = r1.x; RT[ 5 * KP2] = r1.y; RT[ 6 * KP2] = r1.z; RT[ 7 * KP2] = r1.w;
            RT[ 8 * KP2] = r2.x; RT[ 9 * KP2] = r2.y; RT[10 * KP2] = r2.z; RT[11 * KP2] = r2.w;
            RT[12 * KP2] = r3.x; RT[13 * KP2] = r3.y; RT[14 * KP2] = r3.z; RT[15 * KP2] = r3.w;
        } else {
            xl0 = 0.0f; xl1 = 0.0f; xl2 = 0.0f;
#pragma unroll
            for (int w = 0; w < 16; ++w) RT[w * KP2] = 0u;
        }
        xlg[(size_t)(b * KP2 + t)] = make_float4(xl0, xl1, xl2, 0.0f);
    }
}

// ---------------------------------------------------------------------------
// K5: GAT -- grid (16,52) x 512, one wave per output row, no LDS (r19 verbatim).
__global__ __launch_bounds__(512) void r19_gat(
    const float* __restrict__ xpg,
    const float4* __restrict__ xlg,
    const int* __restrict__ kidxg,
    const uint32_t* __restrict__ RTg,
    const float* __restrict__ gwr, const float* __restrict__ gbr,
    const float* __restrict__ gatt, const float* __restrict__ gbias,
    float* __restrict__ g_raw)
{
    const int b = blockIdx.x, y = blockIdx.y, t = threadIdx.x;
    const int lane = t & 63, wv = t >> 6;
    const int i = y * 8 + wv;                  // row of this wave
    if (i >= KKk) return;

    float Wr[9];
#pragma unroll
    for (int k = 0; k < 9; ++k) Wr[k] = gwr[k];
    const float Br0 = gbr[0], Br1 = gbr[1], Br2 = gbr[2];
    const float At0 = gatt[0], At1 = gatt[1], At2 = gatt[2];
    const float Gb0 = gbias[0], Gb1 = gbias[1], Gb2 = gbias[2];

    const int bi = kidxg[b * KPAD + i];
    const float c0 = xpg[(size_t)(b * KPAD + i) * 3 + 0];
    const float c1 = xpg[(size_t)(b * KPAD + i) * 3 + 1];
    const float c2 = xpg[(size_t)(b * KPAD + i) * 3 + 2];
    const float xr0 = c0 * Wr[0] + c1 * Wr[3] + c2 * Wr[6] + Br0;
    const float xr1 = c0 * Wr[1] + c1 * Wr[4] + c2 * Wr[7] + Br1;
    const float xr2 = c0 * Wr[2] + c1 * Wr[5] + c2 * Wr[8] + Br2;

    const uint32_t mbit = 1u << (bi & 31);
    const uint32_t* Rw = RTg + (size_t)(b * 16 + (bi >> 5)) * KP2;
    const float4* xlb = xlg + (size_t)b * KP2;

    float mx = -3e38f, lsum = 0.0f, b0 = 0.0f, b1 = 0.0f, b2 = 0.0f;
#pragma unroll
    for (int it = 0; it < 7; ++it) {
        const int j = lane + it * 64;          // < 448, coalesced
        const uint32_t rw = Rw[j];
        const float4 xlv = xlb[j];
        const float xl0 = xlv.x, xl1 = xlv.y, xl2 = xlv.z;
        const bool valid = (rw & mbit) || (j == i);   // pads auto-invalid
        float e0 = xr0 + xl0; e0 = e0 > 0.0f ? e0 : 0.2f * e0;
        float e1 = xr1 + xl1; e1 = e1 > 0.0f ? e1 : 0.2f * e1;
        float e2 = xr2 + xl2; e2 = e2 > 0.0f ? e2 : 0.2f * e2;
        const float sv = At0 * e0 + At1 * e1 + At2 * e2;
        if (valid) {
            if (sv > mx) {
                const float r = __expf(mx - sv);
                lsum *= r; b0 *= r; b1 *= r; b2 *= r;
                mx = sv;
            }
            const float pj = __expf(sv - mx);
            lsum += pj;
            b0 += pj * xl0; b1 += pj * xl1; b2 += pj * xl2;
        }
    }
#pragma unroll
    for (int off = 32; off; off >>= 1) {       // butterfly LSE merge
        const float mo = __shfl_xor(mx, off);
        const float lo = __shfl_xor(lsum, off);
        const float d0 = __shfl_xor(b0, off);
        const float d1 = __shfl_xor(b1, off);
        const float d2 = __shfl_xor(b2, off);
        const float M  = fmaxf(mx, mo);
        const float ea = __expf(mx - M), eb = __expf(mo - M);
        lsum = lsum * ea + lo * eb;
        b0 = b0 * ea + d0 * eb;
        b1 = b1 * ea + d1 * eb;
        b2 = b2 * ea + d2 * eb;
        mx = M;
    }
    if (lane == 0) {
        const float rl = 1.0f / fmaxf(lsum, 1e-30f);
        g_raw[(size_t)(b * KPAD + i) * 3 + 0] = r17_sane(b0 * rl + Gb0);
        g_raw[(size_t)(b * KPAD + i) * 3 + 1] = r17_sane(b1 * rl + Gb1);
        g_raw[(size_t)(b * KPAD + i) * 3 + 2] = r17_sane(b2 * rl + Gb2);
    }
}

// ---------------------------------------------------------------------------
// K6: head (r17_head verbatim).
__global__ __launch_bounds__(512) void r17_head(
    const float* __restrict__ g_raw,
    const float* __restrict__ x1,
    const float* __restrict__ x,
    const int* __restrict__ cnid,
    const int* __restrict__ amask,
    const float* n2w, const float* n2b, const float* n2ms,
    const float* v1w, const float* v1b,
    const float* v2w, const float* v2b,
    const float* v3w, const float* v3b,
    const float* a1w, const float* a1b,
    const float* a2w, const float* a2b,
    const float* a3w, const float* a3b,
    float* __restrict__ out)
{
    __shared__ float wred[24];
    __shared__ float mv[6];
    __shared__ float gp[3];
    __shared__ float feat[19];
    __shared__ float h1a[10], h1v[10], h2a[5], h2v[5];
    __shared__ float a3[50];
    __shared__ float vout_s, amean_s;
    const int b = blockIdx.x, t = threadIdx.x;
    const int lane = t & 63, wv = t >> 6;
    const float denom = 1.0f / (float)(BB * KKk);

    float gv0[13], gv1[13], gv2[13];
    float p0 = 0.0f, p1 = 0.0f, p2 = 0.0f;
#pragma unroll
    for (int k = 0; k < 13; ++k) {
        const int r = k * 512 + t;
        float q0 = 0.0f, q1 = 0.0f, q2 = 0.0f;
        if (r < BB * KKk) {
            const int bq = r / KKk, iq = r - bq * KKk;
            const float* gr = g_raw + (size_t)(bq * KPAD + iq) * 3;
            q0 = gr[0]; q1 = gr[1]; q2 = gr[2];
        }
        gv0[k] = q0; gv1[k] = q1; gv2[k] = q2;
        p0 += q0; p1 += q1; p2 += q2;
    }
#pragma unroll
    for (int off = 32; off; off >>= 1) {
        p0 += __shfl_xor(p0, off); p1 += __shfl_xor(p1, off); p2 += __shfl_xor(p2, off);
    }
    if (lane == 0) { wred[wv * 3 + 0] = p0; wred[wv * 3 + 1] = p1; wred[wv * 3 + 2] = p2; }
    __syncthreads();
    if (t < 3) {
        float s = 0.0f;
        for (int w = 0; w < 8; ++w) s += wred[w * 3 + t];
        mv[t] = s * denom;
    }
    __syncthreads();
    const float mm0 = n2ms[0] * mv[0], mm1 = n2ms[1] * mv[1], mm2 = n2ms[2] * mv[2];
    float q0a = 0.0f, q1a = 0.0f, q2a = 0.0f;
#pragma unroll
    for (int k = 0; k < 13; ++k) {
        const int r = k * 512 + t;
        if (r < BB * KKk) {
            const float d0 = gv0[k] - mm0, d1 = gv1[k] - mm1, d2 = gv2[k] - mm2;
            q0a += d0 * d0; q1a += d1 * d1; q2a += d2 * d2;
        }
    }
#pragma unroll
    for (int off = 32; off; off >>= 1) {
        q0a += __shfl_xor(q0a, off); q1a += __shfl_xor(q1a, off); q2a += __shfl_xor(q2a, off);
    }
    if (lane == 0) { wred[wv * 3 + 0] = q0a; wred[wv * 3 + 1] = q1a; wred[wv * 3 + 2] = q2a; }
    __syncthreads();
    if (t < 3) {
        float s = 0.0f;
        for (int w = 0; w < 8; ++w) s += wred[w * 3 + t];
        mv[3 + t] = s * denom;
    }
    __syncthreads();

    const float mmv[3] = { mm0, mm1, mm2 };
    float s3[3] = { 0.0f, 0.0f, 0.0f };
    if (t < KKk) {
        const size_t r = (size_t)(b * KPAD + t) * 3;
#pragma unroll
        for (int c = 0; c < 3; ++c) {
            const float iv = 1.0f / sqrtf(fmaxf(mv[3 + c], 0.0f) + EPSf);
            s3[c] = fmaxf((g_raw[r + c] - mmv[c]) * iv * n2w[c] + n2b[c], 0.0f);
        }
    }
    float g0 = s3[0], g1 = s3[1], g2 = s3[2];
#pragma unroll
    for (int off = 32; off; off >>= 1) {
        g0 += __shfl_xor(g0, off); g1 += __shfl_xor(g1, off); g2 += __shfl_xor(g2, off);
    }
    if (lane == 0) { wred[wv * 3 + 0] = g0; wred[wv * 3 + 1] = g1; wred[wv * 3 + 2] = g2; }
    __syncthreads();
    if (t < 3) {
        float s = 0.0f;
        for (int w = 0; w < 8; ++w) s += wred[w * 3 + t];
        gp[t] = s;
    }
    __syncthreads();

    if (t < 19) {
        const int gidx = cnid[b] + b * KKk;        // faithful: pooled-K offsets
        float fv;
        if (t < 13)      fv = x[(size_t)gidx * NFf + t];
        else if (t < 16) fv = x1[(size_t)gidx * 3 + (t - 13)];
        else             fv = gp[t - 16];
        feat[t] = fv;
    }
    __syncthreads();

    if (t < 10) {
        float s = a1b[t];
        for (int f = 0; f < 19; ++f) s += feat[f] * a1w[f * 10 + t];
        h1a[t] = fmaxf(s, 0.0f);
    } else if (t >= 64 && t < 74) {
        const int j = t - 64;
        float s = v1b[j];
        for (int f = 0; f < 19; ++f) s += feat[f] * v1w[f * 10 + j];
        h1v[j] = fmaxf(s, 0.0f);
    }
    __syncthreads();
    if (t < 5) {
        float s = a2b[t];
        for (int k = 0; k < 10; ++k) s += h1a[k] * a2w[k * 5 + t];
        h2a[t] = fmaxf(s, 0.0f);
    } else if (t >= 64 && t < 69) {
        const int j = t - 64;
        float s = v2b[j];
        for (int k = 0; k < 10; ++k) s += h1v[k] * v2w[k * 5 + j];
        h2v[j] = fmaxf(s, 0.0f);
    }
    __syncthreads();
    if (t < 50) {
        float s = a3b[t];
        for (int k = 0; k < 5; ++k) s += h2a[k] * a3w[k * 50 + t];
        a3[t] = s;
    } else if (t == 64) {
        float s = v3b[0];
        for (int k = 0; k < 5; ++k) s += h2v[k] * v3w[k];
        vout_s = s;
    }
    __syncthreads();
    if (t == 0) {
        float s = 0.0f;
        for (int k = 0; k < 50; ++k) s += a3[k];
        amean_s = s * (1.0f / 50.0f);
    }
    __syncthreads();
    if (t < 50) {
        float q = vout_s + a3[t] - amean_s;
        if (!(q == q)) q = 0.0f;
        q = fminf(fmaxf(q, -QCLMP), QCLMP);
        out[b * NAa + t] = (amask[b * NAa + t] == 0) ? -1e8f : q;   // FP32
    }
}

// ---------------------------------------------------------------------------
extern "C" void kernel_launch(void* const* d_in, const int* in_sizes, int n_in,
                              void* d_out, int out_size, void* d_ws, size_t ws_size,
                              hipStream_t stream) {
    (void)in_sizes; (void)n_in; (void)out_size;
    const float* x     = (const float*)d_in[0];
    const int* ei      = (const int*)d_in[1];
    const int* cnid    = (const int*)d_in[4];
    const int* amask   = (const int*)d_in[5];
    const float* panw  = (const float*)d_in[6];
    const float* l1w   = (const float*)d_in[7];
    const float* l1b   = (const float*)d_in[8];
    const float* n1w   = (const float*)d_in[9];
    const float* n1b   = (const float*)d_in[10];
    const float* n1ms  = (const float*)d_in[11];
    const float* poolp = (const float*)d_in[12];
    const float* poolb = (const float*)d_in[13];
    const float* gwl   = (const float*)d_in[14];
    const float* gbl   = (const float*)d_in[15];
    const float* gwr   = (const float*)d_in[16];
    const float* gbr   = (const float*)d_in[17];
    const float* gatt  = (const float*)d_in[18];
    const float* gbias = (const float*)d_in[19];
    const float* n2w   = (const float*)d_in[20];
    const float* n2b   = (const float*)d_in[21];
    const float* n2ms  = (const float*)d_in[22];
    const float* v1w   = (const float*)d_in[23];
    const float* v1b   = (const float*)d_in[24];
    const float* v2w   = (const float*)d_in[25];
    const float* v2b   = (const float*)d_in[26];
    const float* v3w   = (const float*)d_in[27];
    const float* v3b   = (const float*)d_in[28];
    const float* a1w   = (const float*)d_in[29];
    const float* a1b   = (const float*)d_in[30];
    const float* a2w   = (const float*)d_in[31];
    const float* a2b   = (const float*)d_in[32];
    const float* a3w   = (const float*)d_in[33];
    const float* a3b   = (const float*)d_in[34];
    float* out         = (float*)d_out;

    // ws layout (bytes): fwdb 512K | trsb 512K | Rb 512K | csrF | csrT | d0g |
    //                    h_raw | x1 | colsum | g_raw | xpg | xlg(f4) | kidxg | RTg
    uint8_t* wsb = (uint8_t*)d_ws;
    uint32_t* fwdb = (uint32_t*)wsb;
    uint32_t* trsb = (uint32_t*)(wsb + 524288);
    uint32_t* Rb   = (uint32_t*)(wsb + 1048576);
    unsigned short* csrF = (unsigned short*)(wsb + 1572864);
    unsigned short* csrT = csrF + (size_t)MAXD * 8192;
    float* d0g    = (float*)(csrT + (size_t)MAXD * 8192);
    float* h_raw  = d0g + NNt;
    float* x1     = h_raw + (size_t)NNt * 3;
    float* colsum = x1 + (size_t)NNt * 3;
    float* g_raw  = colsum + NNt;
    float* xpg    = g_raw + (size_t)BB * KPAD * 3;
    float4* xlg   = (float4*)(xpg + (size_t)BB * KPAD * 3);
    int*   kidxg  = (int*)(xlg + (size_t)BB * KP2);
    uint32_t* RTg = (uint32_t*)(kidxg + (size_t)BB * KPAD);
    const size_t needed = (size_t)((uint8_t*)(RTg + (size_t)BB * 16 * KP2) - wsb);
    if (ws_size < needed) return;

    hipMemsetAsync(fwdb, 0, 1048576, stream);            // both bitsets
    r17_scatter<<<dim3((EEe + 255) / 256), dim3(256), 0, stream>>>(ei, fwdb, trsb);
    r24_extract<<<dim3(176), dim3(512), 0, stream>>>(fwdb, trsb, panw,
                                                     csrF, csrT, d0g, Rb);
    r24_mid<<<dim3(16, 4), dim3(512), 0, stream>>>(x, csrF, csrT, panw, l1w, l1b,
                                                   d0g, h_raw, colsum);
    r19_pool<<<dim3(16), dim3(512), 0, stream>>>(h_raw, colsum, Rb,
                                                 n1w, n1b, n1ms, poolp, poolb,
                                                 gwl, gbl,
                                                 x1, xpg, xlg, kidxg, RTg);
    r19_gat<<<dim3(16, 52), dim3(512), 0, stream>>>(xpg, xlg, kidxg, RTg,
                                                    gwr, gbr, gatt, gbias, g_raw);
    r17_head<<<dim3(16), dim3(512), 0, stream>>>(g_raw, x1, x, cnid, amask,
                                                 n2w, n2b, n2ms, v1w, v1b, v2w, v2b, v3w, v3b,
                                                 a1w, a1b, a2w, a2b, a3w, a3b, out);
}